// Round 1
// baseline (1139.103 us; speedup 1.0000x reference)
//
#include <hip/hip_runtime.h>
#include <stdint.h>

typedef unsigned short u16;
typedef unsigned int u32;
typedef __attribute__((ext_vector_type(8))) short bf16x8;
typedef __attribute__((ext_vector_type(8))) unsigned short u16x8;
typedef __attribute__((ext_vector_type(4))) float f32x4;

#define LB256 __launch_bounds__(256, 2)

// ---- problem dims ----
#define BB 4
#define NX 1024
#define NC 154
#define NT 1178
#define NTP 1184   // padded t stride for V^T (16B-aligned rows)
#define DD 1536
#define HH 24
#define MHD 6144
#define NQKV 4608
#define NMOD 9216

__device__ __forceinline__ int imin(int a, int b) { return a < b ? a : b; }

__device__ __forceinline__ u16 f2bf(float f) {
  u32 u = __float_as_uint(f);
  u32 r = (u + 0x7fffu + ((u >> 16) & 1u)) >> 16;
  return (u16)r;
}

__device__ __forceinline__ float gelu_t(float x) {
  float x2 = x * x;
  float t = tanhf(0.7978845608028654f * x * (1.f + 0.044715f * x2));
  return 0.5f * x * (1.f + t);
}

__device__ __forceinline__ f32x4 fzero4() {
  f32x4 z; z[0] = 0.f; z[1] = 0.f; z[2] = 0.f; z[3] = 0.f; return z;
}

// ---- weight transpose + f32->bf16: W[K][N] -> Wt[N][K] ----
__global__ void k_transpose(const float* __restrict__ W, u16* __restrict__ Wt, int K, int N) {
  __shared__ float tile[32][33];
  int n0 = blockIdx.x * 32, k0 = blockIdx.y * 32;
  int tx = threadIdx.x & 31, ty = threadIdx.x >> 5;  // 32 x 8
#pragma unroll
  for (int j = 0; j < 32; j += 8)
    tile[ty + j][tx] = W[(size_t)(k0 + ty + j) * N + n0 + tx];
  __syncthreads();
#pragma unroll
  for (int j = 0; j < 32; j += 8)
    Wt[(size_t)(n0 + ty + j) * K + k0 + tx] = f2bf(tile[tx][ty + j]);
}

// ---- mod = silu(vec) @ w_mod + b_mod : (4 x 9216) ----
__global__ void k_mod(const float* __restrict__ vec, const float* __restrict__ w_mod,
                      const float* __restrict__ b_mod, float* __restrict__ mod) {
  __shared__ float sv[BB][DD];
  int n = blockIdx.x * 256 + threadIdx.x;
  for (int i = threadIdx.x; i < BB * DD; i += 256) {
    float v = vec[i];
    sv[i / DD][i % DD] = v / (1.f + __expf(-v));
  }
  __syncthreads();
  float a0 = 0.f, a1 = 0.f, a2 = 0.f, a3 = 0.f;
  for (int k = 0; k < DD; ++k) {
    float w = w_mod[(size_t)k * NMOD + n];
    a0 = fmaf(sv[0][k], w, a0);
    a1 = fmaf(sv[1][k], w, a1);
    a2 = fmaf(sv[2][k], w, a2);
    a3 = fmaf(sv[3][k], w, a3);
  }
  float bb = b_mod[n];
  mod[0 * NMOD + n] = a0 + bb;
  mod[1 * NMOD + n] = a1 + bb;
  mod[2 * NMOD + n] = a2 + bb;
  mod[3 * NMOD + n] = a3 + bb;
}

// ---- LayerNorm (optionally modulated) f32 -> bf16 ----
__global__ LB256 void k_ln(const float* __restrict__ in, u16* __restrict__ out,
                           const float* __restrict__ modp, int sh_off, int sc_off,
                           int rows_per_b) {
  int row = blockIdx.x;
  int b = row / rows_per_b;
  const float* xr = in + (size_t)row * DD;
  float v[6];
  float s = 0.f, s2 = 0.f;
#pragma unroll
  for (int i = 0; i < 6; ++i) {
    float t = xr[threadIdx.x + 256 * i];
    v[i] = t; s += t; s2 += t * t;
  }
#pragma unroll
  for (int m = 32; m >= 1; m >>= 1) {
    s += __shfl_xor(s, m);
    s2 += __shfl_xor(s2, m);
  }
  __shared__ float red[8];
  int wid = threadIdx.x >> 6;
  if ((threadIdx.x & 63) == 0) { red[wid] = s; red[4 + wid] = s2; }
  __syncthreads();
  s = red[0] + red[1] + red[2] + red[3];
  s2 = red[4] + red[5] + red[6] + red[7];
  float mean = s * (1.f / (float)DD);
  float var = s2 * (1.f / (float)DD) - mean * mean;
  float rstd = rsqrtf(var + 1e-6f);
#pragma unroll
  for (int i = 0; i < 6; ++i) {
    int d = threadIdx.x + 256 * i;
    float y = (v[i] - mean) * rstd;
    if (modp) y = y * (1.f + modp[b * NMOD + sc_off + d]) + modp[b * NMOD + sh_off + d];
    out[(size_t)row * DD + d] = f2bf(y);
  }
}

// ---- generic bf16 MFMA GEMM: C = A(MxK) @ Bt(NxK)^T + bias, 128x128x32 tile ----
// EPI: 0 bias->bf16 | 1 gelu(bias)->bf16 | 2 resid + g*(acc+bias) -> f32 | 3 resid + acc + bias -> f32
template <int EPI>
__global__ LB256 void k_gemm(const u16* __restrict__ A, const u16* __restrict__ Bt,
                             const float* __restrict__ bias, int M, int N, int K,
                             void* __restrict__ outp, const float* __restrict__ resid,
                             const float* __restrict__ modp, int goff, int rows_per_b) {
  __shared__ __align__(16) u16 As[128 * 32];
  __shared__ __align__(16) u16 Bs[128 * 32];
  const int tid = threadIdx.x;
  const int lane = tid & 63;
  const int g = lane >> 4, r = lane & 15;
  const int wid = tid >> 6;
  const int m0 = blockIdx.y * 128, n0 = blockIdx.x * 128;
  const int wm = (wid >> 1) * 64, wn = (wid & 1) * 64;

  f32x4 acc[4][4];
#pragma unroll
  for (int i = 0; i < 4; ++i)
#pragma unroll
    for (int j = 0; j < 4; ++j) acc[i][j] = fzero4();

  const int arow = tid >> 2;           // 0..63
  const int kcol = (tid & 3) * 8;      // ushort offset within K window
  const size_t a_r0 = (size_t)imin(m0 + arow, M - 1) * K;
  const size_t a_r1 = (size_t)imin(m0 + 64 + arow, M - 1) * K;
  const size_t b_r0 = (size_t)(n0 + arow) * K;
  const size_t b_r1 = (size_t)(n0 + 64 + arow) * K;

  for (int k0 = 0; k0 < K; k0 += 32) {
    u16x8 av0 = *(const u16x8*)(A + a_r0 + k0 + kcol);
    u16x8 av1 = *(const u16x8*)(A + a_r1 + k0 + kcol);
    u16x8 bv0 = *(const u16x8*)(Bt + b_r0 + k0 + kcol);
    u16x8 bv1 = *(const u16x8*)(Bt + b_r1 + k0 + kcol);
    __syncthreads();
    *(u16x8*)&As[arow * 32 + kcol] = av0;
    *(u16x8*)&As[(64 + arow) * 32 + kcol] = av1;
    *(u16x8*)&Bs[arow * 32 + kcol] = bv0;
    *(u16x8*)&Bs[(64 + arow) * 32 + kcol] = bv1;
    __syncthreads();
    bf16x8 af[4], bfr[4];
#pragma unroll
    for (int mi = 0; mi < 4; ++mi) af[mi] = *(const bf16x8*)&As[(wm + mi * 16 + r) * 32 + g * 8];
#pragma unroll
    for (int ni = 0; ni < 4; ++ni) bfr[ni] = *(const bf16x8*)&Bs[(wn + ni * 16 + r) * 32 + g * 8];
#pragma unroll
    for (int mi = 0; mi < 4; ++mi)
#pragma unroll
      for (int ni = 0; ni < 4; ++ni)
        acc[mi][ni] = __builtin_amdgcn_mfma_f32_16x16x32_bf16(af[mi], bfr[ni], acc[mi][ni], 0, 0, 0);
  }

#pragma unroll
  for (int mi = 0; mi < 4; ++mi) {
#pragma unroll
    for (int ni = 0; ni < 4; ++ni) {
      const int col = n0 + wn + ni * 16 + r;
      const float bv = bias[col];
#pragma unroll
      for (int j = 0; j < 4; ++j) {
        const int row = m0 + wm + mi * 16 + g * 4 + j;
        if (row >= M) continue;
        float v = acc[mi][ni][j] + bv;
        const size_t off = (size_t)row * N + col;
        if constexpr (EPI == 0) {
          ((u16*)outp)[off] = f2bf(v);
        } else if constexpr (EPI == 1) {
          ((u16*)outp)[off] = f2bf(gelu_t(v));
        } else if constexpr (EPI == 2) {
          const int b = row / rows_per_b;
          ((float*)outp)[off] = resid[off] + modp[b * NMOD + goff + col] * v;
        } else {
          ((float*)outp)[off] = resid[off] + v;
        }
      }
    }
  }
}

// ---- scatter qkv GEMM output into q,k (b,h,t,d) bf16 ----
__global__ void k_qk(const u16* __restrict__ qkvx, const u16* __restrict__ qkvc,
                     u16* __restrict__ q, u16* __restrict__ k) {
  int idx = blockIdx.x * 256 + threadIdx.x;
  if (idx >= NT * 64) return;
  int t = idx >> 6, d = idx & 63;
  int h = blockIdx.y, b = blockIdx.z;
  const u16* src = (t < NX) ? qkvx + (size_t)(b * NX + t) * NQKV
                            : qkvc + (size_t)(b * NC + t - NX) * NQKV;
  size_t o = ((size_t)(b * HH + h) * NT + t) * 64 + d;
  q[o] = src[h * 64 + d];
  k[o] = src[DD + h * 64 + d];
}

// ---- V transpose: qkv v-cols -> vt (b,h,d,t) bf16, t-stride NTP ----
__global__ void k_vt(const u16* __restrict__ qkvx, const u16* __restrict__ qkvc,
                     u16* __restrict__ vt) {
  __shared__ u16 tile[64][65];
  int t0 = blockIdx.x * 64;
  int h = blockIdx.y, b = blockIdx.z;
  int tx = threadIdx.x & 63, ty = threadIdx.x >> 6;
#pragma unroll
  for (int j = 0; j < 16; ++j) {
    int tt = ty * 16 + j;
    int t = t0 + tt;
    if (t < NT) {
      const u16* src = (t < NX) ? qkvx + (size_t)(b * NX + t) * NQKV
                                : qkvc + (size_t)(b * NC + t - NX) * NQKV;
      tile[tt][tx] = src[2 * DD + h * 64 + tx];
    }
  }
  __syncthreads();
  size_t base = (size_t)(b * HH + h) * 64 * NTP;
#pragma unroll
  for (int j = 0; j < 16; ++j) {
    int dd = ty * 16 + j;
    int t = t0 + tx;
    if (t < NT) vt[base + (size_t)dd * NTP + t] = tile[tx][dd];
  }
}

// ---- flash attention: QBLK=64 (4 waves x 16 rows), KBLK=64, HD=64 ----
__global__ LB256 void k_attn(const u16* __restrict__ q, const u16* __restrict__ kk,
                             const u16* __restrict__ vt, u16* __restrict__ ox,
                             u16* __restrict__ oc) {
  __shared__ __align__(16) u16 Ks[64][72];
  __shared__ __align__(16) u16 Vs[64][72];
  __shared__ __align__(16) u16 Ps[4][16][72];

  const int lane = threadIdx.x & 63, wid = threadIdx.x >> 6;
  const int g = lane >> 4, r = lane & 15;
  const int q0 = blockIdx.x * 64;
  const int h = blockIdx.y, b = blockIdx.z;
  const size_t bh = (size_t)b * HH + h;
  const u16* qp = q + bh * (NT * 64);
  const u16* kp = kk + bh * (NT * 64);
  const u16* vp = vt + bh * (64 * NTP);

  const int qrow = imin(q0 + wid * 16 + r, NT - 1);
  const bf16x8 qa0 = *(const bf16x8*)(qp + (size_t)qrow * 64 + g * 8);
  const bf16x8 qa1 = *(const bf16x8*)(qp + (size_t)qrow * 64 + 32 + g * 8);

  f32x4 oacc[4];
#pragma unroll
  for (int i = 0; i < 4; ++i) oacc[i] = fzero4();
  float mrow[4], lrow[4];
#pragma unroll
  for (int j = 0; j < 4; ++j) { mrow[j] = -1e30f; lrow[j] = 0.f; }

  for (int t0 = 0; t0 < NT; t0 += 64) {
    u16x8 kreg[2], vreg[2];
    int tr0[2], cc0[2];
#pragma unroll
    for (int p = 0; p < 2; ++p) {
      int chunk = p * 256 + threadIdx.x;
      tr0[p] = chunk >> 3;
      cc0[p] = (chunk & 7) * 8;
      int tsrc = imin(t0 + tr0[p], NT - 1);
      kreg[p] = *(const u16x8*)(kp + (size_t)tsrc * 64 + cc0[p]);
      int tcol = t0 + cc0[p];
      if (tcol + 8 <= NT) {
        vreg[p] = *(const u16x8*)(vp + (size_t)tr0[p] * NTP + tcol);
      } else {
#pragma unroll
        for (int e = 0; e < 8; ++e)
          vreg[p][e] = vp[(size_t)tr0[p] * NTP + imin(tcol + e, NT - 1)];
      }
    }
    __syncthreads();
#pragma unroll
    for (int p = 0; p < 2; ++p) {
      *(u16x8*)&Ks[tr0[p]][cc0[p]] = kreg[p];
      *(u16x8*)&Vs[tr0[p]][cc0[p]] = vreg[p];
    }
    __syncthreads();

    // S = Q K^T * scale
    f32x4 s[4];
#pragma unroll
    for (int ni = 0; ni < 4; ++ni) {
      s[ni] = fzero4();
      s[ni] = __builtin_amdgcn_mfma_f32_16x16x32_bf16(qa0, *(const bf16x8*)&Ks[ni * 16 + r][g * 8], s[ni], 0, 0, 0);
      s[ni] = __builtin_amdgcn_mfma_f32_16x16x32_bf16(qa1, *(const bf16x8*)&Ks[ni * 16 + r][32 + g * 8], s[ni], 0, 0, 0);
    }

    float pv[4][4], pm[4];
#pragma unroll
    for (int j = 0; j < 4; ++j) pm[j] = -1e30f;
#pragma unroll
    for (int ni = 0; ni < 4; ++ni) {
      int tcol = t0 + ni * 16 + r;
      bool ok = tcol < NT;
#pragma unroll
      for (int j = 0; j < 4; ++j) {
        float sv = ok ? s[ni][j] * 0.125f : -1e30f;
        pv[ni][j] = sv;
        pm[j] = fmaxf(pm[j], sv);
      }
    }
#pragma unroll
    for (int j = 0; j < 4; ++j) {
#pragma unroll
      for (int msk = 1; msk <= 8; msk <<= 1) pm[j] = fmaxf(pm[j], __shfl_xor(pm[j], msk));
    }
    float alpha[4], rs[4];
#pragma unroll
    for (int j = 0; j < 4; ++j) {
      float mn = fmaxf(mrow[j], pm[j]);
      alpha[j] = __expf(mrow[j] - mn);
      mrow[j] = mn;
      rs[j] = 0.f;
    }
#pragma unroll
    for (int ni = 0; ni < 4; ++ni)
#pragma unroll
      for (int j = 0; j < 4; ++j) {
        float p = __expf(pv[ni][j] - mrow[j]);
        pv[ni][j] = p;
        rs[j] += p;
      }
#pragma unroll
    for (int j = 0; j < 4; ++j) {
#pragma unroll
      for (int msk = 1; msk <= 8; msk <<= 1) rs[j] += __shfl_xor(rs[j], msk);
      lrow[j] = lrow[j] * alpha[j] + rs[j];
    }
#pragma unroll
    for (int ni = 0; ni < 4; ++ni)
#pragma unroll
      for (int j = 0; j < 4; ++j) oacc[ni][j] *= alpha[j];

    // P -> per-wave LDS (bf16), re-read as A fragment
#pragma unroll
    for (int ni = 0; ni < 4; ++ni)
#pragma unroll
      for (int j = 0; j < 4; ++j)
        Ps[wid][g * 4 + j][ni * 16 + r] = f2bf(pv[ni][j]);

    bf16x8 pa0 = *(const bf16x8*)&Ps[wid][r][g * 8];
    bf16x8 pa1 = *(const bf16x8*)&Ps[wid][r][32 + g * 8];
#pragma unroll
    for (int ni = 0; ni < 4; ++ni) {
      oacc[ni] = __builtin_amdgcn_mfma_f32_16x16x32_bf16(pa0, *(const bf16x8*)&Vs[ni * 16 + r][g * 8], oacc[ni], 0, 0, 0);
      oacc[ni] = __builtin_amdgcn_mfma_f32_16x16x32_bf16(pa1, *(const bf16x8*)&Vs[ni * 16 + r][32 + g * 8], oacc[ni], 0, 0, 0);
    }
  }

#pragma unroll
  for (int ni = 0; ni < 4; ++ni)
#pragma unroll
    for (int j = 0; j < 4; ++j) {
      int tq = q0 + wid * 16 + g * 4 + j;
      if (tq >= NT) continue;
      float val = oacc[ni][j] / lrow[j];
      int col = h * 64 + ni * 16 + r;
      if (tq < NX)
        ox[(size_t)(b * NX + tq) * DD + col] = f2bf(val);
      else
        oc[(size_t)(b * NC + tq - NX) * DD + col] = f2bf(val);
    }
}

extern "C" void kernel_launch(void* const* d_in, const int* in_sizes, int n_in,
                              void* d_out, int out_size, void* d_ws, size_t ws_size,
                              hipStream_t stream) {
  const float* x = (const float*)d_in[0];
  const float* c = (const float*)d_in[1];
  const float* vec = (const float*)d_in[2];
  const float* w_mod = (const float*)d_in[3];
  const float* b_mod = (const float*)d_in[4];
  const float* w_qkv_x = (const float*)d_in[5];
  const float* b_qkv_x = (const float*)d_in[6];
  const float* w_qkv_c = (const float*)d_in[7];
  const float* b_qkv_c = (const float*)d_in[8];
  const float* w_proj_x = (const float*)d_in[9];
  const float* b_proj_x = (const float*)d_in[10];
  const float* w_proj_c = (const float*)d_in[11];
  const float* b_proj_c = (const float*)d_in[12];
  const float* w1_x = (const float*)d_in[13];
  const float* b1_x = (const float*)d_in[14];
  const float* w2_x = (const float*)d_in[15];
  const float* b2_x = (const float*)d_in[16];
  const float* w1_c = (const float*)d_in[17];
  const float* b1_c = (const float*)d_in[18];
  const float* w2_c = (const float*)d_in[19];
  const float* b2_c = (const float*)d_in[20];

  if (ws_size < 229195776ull) return;  // workspace layout below needs this much

  char* ws = (char*)d_ws;
  // persistent: bf16-transposed weights + mod
  u16* wt_qkv_x = (u16*)(ws + 0);
  u16* wt_qkv_c = (u16*)(ws + 14155776);
  u16* wt_proj_x = (u16*)(ws + 28311552);
  u16* wt_proj_c = (u16*)(ws + 33030144);
  u16* wt_w1_x = (u16*)(ws + 37748736);
  u16* wt_w1_c = (u16*)(ws + 56623104);
  u16* wt_w2_x = (u16*)(ws + 75497472);
  u16* wt_w2_c = (u16*)(ws + 94371840);
  float* modf = (float*)(ws + 113246208);
  char* S = ws + 113393664;
  // slot 1 (14,475,264 B): x_n/c_n -> o_x/o_c -> xln/cln
  u16* xn = (u16*)(S);
  u16* cn = (u16*)(S + 12582912);
  // slot 2 (43,425,792 B): qkv_x_out/qkv_c_out -> x2/c2 (f32)
  u16* qkvx = (u16*)(S + 14475264);
  u16* qkvc = (u16*)(S + 52224000);
  float* x2 = (float*)(S + 14475264);
  float* c2 = (float*)(S + 39641088);
  // slot 3 (57,901,056 B): q/k/vt -> h_x/h_c
  u16* qb = (u16*)(S + 57901056);
  u16* kb = (u16*)(S + 72376320);
  u16* vtb = (u16*)(S + 86851584);
  u16* hx = (u16*)(S + 57901056);
  u16* hc = (u16*)(S + 108232704);

  // 1) weights -> bf16 transposed
  k_transpose<<<dim3(NQKV / 32, DD / 32), 256, 0, stream>>>(w_qkv_x, wt_qkv_x, DD, NQKV);
  k_transpose<<<dim3(NQKV / 32, DD / 32), 256, 0, stream>>>(w_qkv_c, wt_qkv_c, DD, NQKV);
  k_transpose<<<dim3(DD / 32, DD / 32), 256, 0, stream>>>(w_proj_x, wt_proj_x, DD, DD);
  k_transpose<<<dim3(DD / 32, DD / 32), 256, 0, stream>>>(w_proj_c, wt_proj_c, DD, DD);
  k_transpose<<<dim3(MHD / 32, DD / 32), 256, 0, stream>>>(w1_x, wt_w1_x, DD, MHD);
  k_transpose<<<dim3(MHD / 32, DD / 32), 256, 0, stream>>>(w1_c, wt_w1_c, DD, MHD);
  k_transpose<<<dim3(DD / 32, MHD / 32), 256, 0, stream>>>(w2_x, wt_w2_x, MHD, DD);
  k_transpose<<<dim3(DD / 32, MHD / 32), 256, 0, stream>>>(w2_c, wt_w2_c, MHD, DD);

  // 2) modulation vector
  k_mod<<<dim3(NMOD / 256), 256, 0, stream>>>(vec, w_mod, b_mod, modf);

  // 3) modulated LN -> bf16
  k_ln<<<dim3(BB * NX), 256, 0, stream>>>(x, xn, modf, 0, DD, NX);
  k_ln<<<dim3(BB * NC), 256, 0, stream>>>(c, cn, modf, 3 * DD, 4 * DD, NC);

  // 4) QKV GEMMs
  k_gemm<0><<<dim3(NQKV / 128, 32), 256, 0, stream>>>(xn, wt_qkv_x, b_qkv_x, BB * NX, NQKV, DD, qkvx, nullptr, nullptr, 0, 1);
  k_gemm<0><<<dim3(NQKV / 128, 5), 256, 0, stream>>>(cn, wt_qkv_c, b_qkv_c, BB * NC, NQKV, DD, qkvc, nullptr, nullptr, 0, 1);

  // 5) reshape to q/k (b,h,t,d) and vt (b,h,d,t)
  k_qk<<<dim3((NT * 64 + 255) / 256, HH, BB), 256, 0, stream>>>(qkvx, qkvc, qb, kb);
  k_vt<<<dim3((NT + 63) / 64, HH, BB), 256, 0, stream>>>(qkvx, qkvc, vtb);

  // 6) flash attention -> o (written into slot 1)
  k_attn<<<dim3((NT + 63) / 64, HH, BB), 256, 0, stream>>>(qb, kb, vtb, xn, cn);

  // 7) output projections with gated residual -> x2/c2 f32
  k_gemm<2><<<dim3(DD / 128, 32), 256, 0, stream>>>(xn, wt_proj_x, b_proj_x, BB * NX, DD, DD, x2, x, modf, 2 * DD, NX);
  k_gemm<2><<<dim3(DD / 128, 5), 256, 0, stream>>>(cn, wt_proj_c, b_proj_c, BB * NC, DD, DD, c2, c, modf, 5 * DD, NC);

  // 8) plain LN -> bf16
  k_ln<<<dim3(BB * NX), 256, 0, stream>>>(x2, xn, nullptr, 0, 0, NX);
  k_ln<<<dim3(BB * NC), 256, 0, stream>>>(c2, cn, nullptr, 0, 0, NC);

  // 9) MLP
  k_gemm<1><<<dim3(MHD / 128, 32), 256, 0, stream>>>(xn, wt_w1_x, b1_x, BB * NX, MHD, DD, hx, nullptr, nullptr, 0, 1);
  k_gemm<1><<<dim3(MHD / 128, 5), 256, 0, stream>>>(cn, wt_w1_c, b1_c, BB * NC, MHD, DD, hc, nullptr, nullptr, 0, 1);

  float* outx = (float*)d_out;
  float* outc = outx + (size_t)BB * NX * DD;
  k_gemm<3><<<dim3(DD / 128, 32), 256, 0, stream>>>(hx, wt_w2_x, b2_x, BB * NX, DD, MHD, outx, x2, nullptr, 0, NX);
  k_gemm<3><<<dim3(DD / 128, 5), 256, 0, stream>>>(hc, wt_w2_c, b2_c, BB * NC, DD, MHD, outc, c2, nullptr, 0, NC);
}

// Round 2
// 1044.000 us; speedup vs baseline: 1.0911x; 1.0911x over previous
//
#include <hip/hip_runtime.h>
#include <stdint.h>

typedef unsigned short u16;
typedef unsigned int u32;
typedef __attribute__((ext_vector_type(8))) short bf16x8;
typedef __attribute__((ext_vector_type(8))) unsigned short u16x8;
typedef __attribute__((ext_vector_type(4))) float f32x4;

#define LB256 __launch_bounds__(256, 2)

// ---- problem dims ----
#define BB 4
#define NX 1024
#define NC 154
#define NT 1178
#define NTP 1184   // padded t stride for V^T (16B-aligned rows)
#define DD 1536
#define HH 24
#define MHD 6144
#define NQKV 4608
#define NMOD 9216
#define KSPL 6

__device__ __forceinline__ int imin(int a, int b) { return a < b ? a : b; }

__device__ __forceinline__ u16 f2bf(float f) {
  u32 u = __float_as_uint(f);
  u32 r = (u + 0x7fffu + ((u >> 16) & 1u)) >> 16;
  return (u16)r;
}

__device__ __forceinline__ float gelu_t(float x) {
  float x2 = x * x;
  float t = tanhf(0.7978845608028654f * x * (1.f + 0.044715f * x2));
  return 0.5f * x * (1.f + t);
}

__device__ __forceinline__ f32x4 fzero4() {
  f32x4 z; z[0] = 0.f; z[1] = 0.f; z[2] = 0.f; z[3] = 0.f; return z;
}

// async global->LDS, 16B per lane; LDS dest = wave-uniform base + lane*16
__device__ __forceinline__ void glds16(const u16* g, u16* l) {
  __builtin_amdgcn_global_load_lds(
      (const __attribute__((address_space(1))) void*)g,
      (__attribute__((address_space(3))) void*)l, 16, 0, 0);
}

// ---- weight transpose + f32->bf16: W[K][N] -> Wt[N][K] ----
__global__ void k_transpose(const float* __restrict__ W, u16* __restrict__ Wt, int K, int N) {
  __shared__ float tile[32][33];
  int n0 = blockIdx.x * 32, k0 = blockIdx.y * 32;
  int tx = threadIdx.x & 31, ty = threadIdx.x >> 5;  // 32 x 8
#pragma unroll
  for (int j = 0; j < 32; j += 8)
    tile[ty + j][tx] = W[(size_t)(k0 + ty + j) * N + n0 + tx];
  __syncthreads();
#pragma unroll
  for (int j = 0; j < 32; j += 8)
    Wt[(size_t)(n0 + ty + j) * K + k0 + tx] = f2bf(tile[tx][ty + j]);
}

// ---- mod = silu(vec) @ w_mod + b_mod : split-K partials (deterministic) ----
__global__ void k_mod_part(const float* __restrict__ vec, const float* __restrict__ w_mod,
                           float* __restrict__ part) {
  __shared__ float sv[BB][256];
  int n = blockIdx.x * 256 + threadIdx.x;
  int kb = blockIdx.y;
  int k0 = kb * 256;
  for (int i = threadIdx.x; i < BB * 256; i += 256) {
    int b = i >> 8, kk = i & 255;
    float v = vec[b * DD + k0 + kk];
    sv[b][kk] = v / (1.f + __expf(-v));
  }
  __syncthreads();
  float a0 = 0.f, a1 = 0.f, a2 = 0.f, a3 = 0.f;
  for (int k = 0; k < 256; ++k) {
    float w = w_mod[(size_t)(k0 + k) * NMOD + n];
    a0 = fmaf(sv[0][k], w, a0);
    a1 = fmaf(sv[1][k], w, a1);
    a2 = fmaf(sv[2][k], w, a2);
    a3 = fmaf(sv[3][k], w, a3);
  }
  part[((size_t)kb * BB + 0) * NMOD + n] = a0;
  part[((size_t)kb * BB + 1) * NMOD + n] = a1;
  part[((size_t)kb * BB + 2) * NMOD + n] = a2;
  part[((size_t)kb * BB + 3) * NMOD + n] = a3;
}

__global__ void k_mod_red(const float* __restrict__ part, const float* __restrict__ b_mod,
                          float* __restrict__ mod) {
  int n = blockIdx.x * 256 + threadIdx.x;
  float bb = b_mod[n];
#pragma unroll
  for (int b = 0; b < BB; ++b) {
    float s = bb;
#pragma unroll
    for (int kb = 0; kb < KSPL; ++kb) s += part[((size_t)kb * BB + b) * NMOD + n];
    mod[b * NMOD + n] = s;
  }
}

// ---- LayerNorm (optionally modulated) f32 -> bf16 ----
__global__ LB256 void k_ln(const float* __restrict__ in, u16* __restrict__ out,
                           const float* __restrict__ modp, int sh_off, int sc_off,
                           int rows_per_b) {
  int row = blockIdx.x;
  int b = row / rows_per_b;
  const float* xr = in + (size_t)row * DD;
  float v[6];
  float s = 0.f, s2 = 0.f;
#pragma unroll
  for (int i = 0; i < 6; ++i) {
    float t = xr[threadIdx.x + 256 * i];
    v[i] = t; s += t; s2 += t * t;
  }
#pragma unroll
  for (int m = 32; m >= 1; m >>= 1) {
    s += __shfl_xor(s, m);
    s2 += __shfl_xor(s2, m);
  }
  __shared__ float red[8];
  int wid = threadIdx.x >> 6;
  if ((threadIdx.x & 63) == 0) { red[wid] = s; red[4 + wid] = s2; }
  __syncthreads();
  s = red[0] + red[1] + red[2] + red[3];
  s2 = red[4] + red[5] + red[6] + red[7];
  float mean = s * (1.f / (float)DD);
  float var = s2 * (1.f / (float)DD) - mean * mean;
  float rstd = rsqrtf(var + 1e-6f);
#pragma unroll
  for (int i = 0; i < 6; ++i) {
    int d = threadIdx.x + 256 * i;
    float y = (v[i] - mean) * rstd;
    if (modp) y = y * (1.f + modp[b * NMOD + sc_off + d]) + modp[b * NMOD + sh_off + d];
    out[(size_t)row * DD + d] = f2bf(y);
  }
}

// ---- generic bf16 MFMA GEMM: C = A(MxK) @ Bt(NxK)^T + bias, 128x128x32 tile ----
// global_load_lds staging (m97 structure). EPI: 0 bias->bf16 | 1 gelu->bf16 |
// 2 resid + g*(acc+bias) -> f32 | 3 resid + acc + bias -> f32
template <int EPI>
__global__ LB256 void k_gemm(const u16* __restrict__ A, const u16* __restrict__ Bt,
                             const float* __restrict__ bias, int M, int N, int K,
                             void* __restrict__ outp, const float* __restrict__ resid,
                             const float* __restrict__ modp, int goff, int rows_per_b) {
  __shared__ __align__(16) u16 As[128 * 32];
  __shared__ __align__(16) u16 Bs[128 * 32];
  const int tid = threadIdx.x;
  const int lane = tid & 63;
  const int g = lane >> 4, r = lane & 15;
  const int wid = tid >> 6;
  const int m0 = blockIdx.y * 128, n0 = blockIdx.x * 128;
  const int wm = (wid >> 1) * 64, wn = (wid & 1) * 64;

  f32x4 acc[4][4];
#pragma unroll
  for (int i = 0; i < 4; ++i)
#pragma unroll
    for (int j = 0; j < 4; ++j) acc[i][j] = fzero4();

  // staging: wave wid writes rows [wid*16, wid*16+16) of each 64-row chunk.
  // lane l -> row wid*16 + l/4, u16 col (l&3)*8 ; LDS dest = base + lane*16B
  const int srow = wid * 16 + (lane >> 2);
  const int kc = (lane & 3) * 8;
  const u16* a0 = A + (size_t)imin(m0 + srow, M - 1) * K + kc;
  const u16* a1 = A + (size_t)imin(m0 + 64 + srow, M - 1) * K + kc;
  const u16* b0 = Bt + (size_t)(n0 + srow) * K + kc;
  const u16* b1 = Bt + (size_t)(n0 + 64 + srow) * K + kc;
  u16* lA0 = &As[wid * 16 * 32];
  u16* lA1 = &As[(64 + wid * 16) * 32];
  u16* lB0 = &Bs[wid * 16 * 32];
  u16* lB1 = &Bs[(64 + wid * 16) * 32];

  for (int k0 = 0; k0 < K; k0 += 32) {
    __syncthreads();
    glds16(a0 + k0, lA0);
    glds16(a1 + k0, lA1);
    glds16(b0 + k0, lB0);
    glds16(b1 + k0, lB1);
    __syncthreads();
    bf16x8 af[4], bfr[4];
#pragma unroll
    for (int mi = 0; mi < 4; ++mi) af[mi] = *(const bf16x8*)&As[(wm + mi * 16 + r) * 32 + g * 8];
#pragma unroll
    for (int ni = 0; ni < 4; ++ni) bfr[ni] = *(const bf16x8*)&Bs[(wn + ni * 16 + r) * 32 + g * 8];
#pragma unroll
    for (int mi = 0; mi < 4; ++mi)
#pragma unroll
      for (int ni = 0; ni < 4; ++ni)
        acc[mi][ni] = __builtin_amdgcn_mfma_f32_16x16x32_bf16(af[mi], bfr[ni], acc[mi][ni], 0, 0, 0);
  }

#pragma unroll
  for (int mi = 0; mi < 4; ++mi) {
#pragma unroll
    for (int ni = 0; ni < 4; ++ni) {
      const int col = n0 + wn + ni * 16 + r;
      const float bv = bias[col];
#pragma unroll
      for (int j = 0; j < 4; ++j) {
        const int row = m0 + wm + mi * 16 + g * 4 + j;
        if (row >= M) continue;
        float v = acc[mi][ni][j] + bv;
        const size_t off = (size_t)row * N + col;
        if constexpr (EPI == 0) {
          ((u16*)outp)[off] = f2bf(v);
        } else if constexpr (EPI == 1) {
          ((u16*)outp)[off] = f2bf(gelu_t(v));
        } else if constexpr (EPI == 2) {
          const int b = row / rows_per_b;
          ((float*)outp)[off] = resid[off] + modp[b * NMOD + goff + col] * v;
        } else {
          ((float*)outp)[off] = resid[off] + v;
        }
      }
    }
  }
}

// ---- scatter qkv GEMM output into q,k (b,h,t,d) bf16 ----
__global__ void k_qk(const u16* __restrict__ qkvx, const u16* __restrict__ qkvc,
                     u16* __restrict__ q, u16* __restrict__ k) {
  int idx = blockIdx.x * 256 + threadIdx.x;
  if (idx >= NT * 64) return;
  int t = idx >> 6, d = idx & 63;
  int h = blockIdx.y, b = blockIdx.z;
  const u16* src = (t < NX) ? qkvx + (size_t)(b * NX + t) * NQKV
                            : qkvc + (size_t)(b * NC + t - NX) * NQKV;
  size_t o = ((size_t)(b * HH + h) * NT + t) * 64 + d;
  q[o] = src[h * 64 + d];
  k[o] = src[DD + h * 64 + d];
}

// ---- V transpose: qkv v-cols -> vt (b,h,d,t) bf16, t-stride NTP ----
__global__ void k_vt(const u16* __restrict__ qkvx, const u16* __restrict__ qkvc,
                     u16* __restrict__ vt) {
  __shared__ u16 tile[64][65];
  int t0 = blockIdx.x * 64;
  int h = blockIdx.y, b = blockIdx.z;
  int tx = threadIdx.x & 63, ty = threadIdx.x >> 6;
#pragma unroll
  for (int j = 0; j < 16; ++j) {
    int tt = ty * 16 + j;
    int t = t0 + tt;
    if (t < NT) {
      const u16* src = (t < NX) ? qkvx + (size_t)(b * NX + t) * NQKV
                                : qkvc + (size_t)(b * NC + t - NX) * NQKV;
      tile[tt][tx] = src[2 * DD + h * 64 + tx];
    }
  }
  __syncthreads();
  size_t base = (size_t)(b * HH + h) * 64 * NTP;
#pragma unroll
  for (int j = 0; j < 16; ++j) {
    int dd = ty * 16 + j;
    int t = t0 + tx;
    if (t < NT) vt[base + (size_t)dd * NTP + t] = tile[tx][dd];
  }
}

// ---- flash attention: QBLK=64 (4 waves x 16 rows), KBLK=64, HD=64 ----
__global__ LB256 void k_attn(const u16* __restrict__ q, const u16* __restrict__ kk,
                             const u16* __restrict__ vt, u16* __restrict__ ox,
                             u16* __restrict__ oc) {
  __shared__ __align__(16) u16 Ks[64][72];
  __shared__ __align__(16) u16 Vs[64][72];
  __shared__ __align__(16) u16 Ps[4][16][72];

  const int lane = threadIdx.x & 63, wid = threadIdx.x >> 6;
  const int g = lane >> 4, r = lane & 15;
  const int q0 = blockIdx.x * 64;
  const int h = blockIdx.y, b = blockIdx.z;
  const size_t bh = (size_t)b * HH + h;
  const u16* qp = q + bh * (NT * 64);
  const u16* kp = kk + bh * (NT * 64);
  const u16* vp = vt + bh * (64 * NTP);

  const int qrow = imin(q0 + wid * 16 + r, NT - 1);
  const bf16x8 qa0 = *(const bf16x8*)(qp + (size_t)qrow * 64 + g * 8);
  const bf16x8 qa1 = *(const bf16x8*)(qp + (size_t)qrow * 64 + 32 + g * 8);

  f32x4 oacc[4];
#pragma unroll
  for (int i = 0; i < 4; ++i) oacc[i] = fzero4();
  float mrow[4], lrow[4];
#pragma unroll
  for (int j = 0; j < 4; ++j) { mrow[j] = -1e30f; lrow[j] = 0.f; }

  for (int t0 = 0; t0 < NT; t0 += 64) {
    u16x8 kreg[2], vreg[2];
    int tr0[2], cc0[2];
#pragma unroll
    for (int p = 0; p < 2; ++p) {
      int chunk = p * 256 + threadIdx.x;
      tr0[p] = chunk >> 3;
      cc0[p] = (chunk & 7) * 8;
      int tsrc = imin(t0 + tr0[p], NT - 1);
      kreg[p] = *(const u16x8*)(kp + (size_t)tsrc * 64 + cc0[p]);
      int tcol = t0 + cc0[p];
      if (tcol + 8 <= NT) {
        vreg[p] = *(const u16x8*)(vp + (size_t)tr0[p] * NTP + tcol);
      } else {
#pragma unroll
        for (int e = 0; e < 8; ++e)
          vreg[p][e] = vp[(size_t)tr0[p] * NTP + imin(tcol + e, NT - 1)];
      }
    }
    __syncthreads();
#pragma unroll
    for (int p = 0; p < 2; ++p) {
      *(u16x8*)&Ks[tr0[p]][cc0[p]] = kreg[p];
      *(u16x8*)&Vs[tr0[p]][cc0[p]] = vreg[p];
    }
    __syncthreads();

    // S = Q K^T * scale
    f32x4 s[4];
#pragma unroll
    for (int ni = 0; ni < 4; ++ni) {
      s[ni] = fzero4();
      s[ni] = __builtin_amdgcn_mfma_f32_16x16x32_bf16(qa0, *(const bf16x8*)&Ks[ni * 16 + r][g * 8], s[ni], 0, 0, 0);
      s[ni] = __builtin_amdgcn_mfma_f32_16x16x32_bf16(qa1, *(const bf16x8*)&Ks[ni * 16 + r][32 + g * 8], s[ni], 0, 0, 0);
    }

    float pv[4][4], pm[4];
#pragma unroll
    for (int j = 0; j < 4; ++j) pm[j] = -1e30f;
#pragma unroll
    for (int ni = 0; ni < 4; ++ni) {
      int tcol = t0 + ni * 16 + r;
      bool ok = tcol < NT;
#pragma unroll
      for (int j = 0; j < 4; ++j) {
        float sv = ok ? s[ni][j] * 0.125f : -1e30f;
        pv[ni][j] = sv;
        pm[j] = fmaxf(pm[j], sv);
      }
    }
#pragma unroll
    for (int j = 0; j < 4; ++j) {
#pragma unroll
      for (int msk = 1; msk <= 8; msk <<= 1) pm[j] = fmaxf(pm[j], __shfl_xor(pm[j], msk));
    }
    float alpha[4], rs[4];
#pragma unroll
    for (int j = 0; j < 4; ++j) {
      float mn = fmaxf(mrow[j], pm[j]);
      alpha[j] = __expf(mrow[j] - mn);
      mrow[j] = mn;
      rs[j] = 0.f;
    }
#pragma unroll
    for (int ni = 0; ni < 4; ++ni)
#pragma unroll
      for (int j = 0; j < 4; ++j) {
        float p = __expf(pv[ni][j] - mrow[j]);
        pv[ni][j] = p;
        rs[j] += p;
      }
#pragma unroll
    for (int j = 0; j < 4; ++j) {
#pragma unroll
      for (int msk = 1; msk <= 8; msk <<= 1) rs[j] += __shfl_xor(rs[j], msk);
      lrow[j] = lrow[j] * alpha[j] + rs[j];
    }
#pragma unroll
    for (int ni = 0; ni < 4; ++ni)
#pragma unroll
      for (int j = 0; j < 4; ++j) oacc[ni][j] *= alpha[j];

    // P -> per-wave LDS (bf16), re-read as A fragment
#pragma unroll
    for (int ni = 0; ni < 4; ++ni)
#pragma unroll
      for (int j = 0; j < 4; ++j)
        Ps[wid][g * 4 + j][ni * 16 + r] = f2bf(pv[ni][j]);

    bf16x8 pa0 = *(const bf16x8*)&Ps[wid][r][g * 8];
    bf16x8 pa1 = *(const bf16x8*)&Ps[wid][r][32 + g * 8];
#pragma unroll
    for (int ni = 0; ni < 4; ++ni) {
      oacc[ni] = __builtin_amdgcn_mfma_f32_16x16x32_bf16(pa0, *(const bf16x8*)&Vs[ni * 16 + r][g * 8], oacc[ni], 0, 0, 0);
      oacc[ni] = __builtin_amdgcn_mfma_f32_16x16x32_bf16(pa1, *(const bf16x8*)&Vs[ni * 16 + r][32 + g * 8], oacc[ni], 0, 0, 0);
    }
  }

#pragma unroll
  for (int ni = 0; ni < 4; ++ni)
#pragma unroll
    for (int j = 0; j < 4; ++j) {
      int tq = q0 + wid * 16 + g * 4 + j;
      if (tq >= NT) continue;
      float val = oacc[ni][j] / lrow[j];
      int col = h * 64 + ni * 16 + r;
      if (tq < NX)
        ox[(size_t)(b * NX + tq) * DD + col] = f2bf(val);
      else
        oc[(size_t)(b * NC + tq - NX) * DD + col] = f2bf(val);
    }
}

extern "C" void kernel_launch(void* const* d_in, const int* in_sizes, int n_in,
                              void* d_out, int out_size, void* d_ws, size_t ws_size,
                              hipStream_t stream) {
  const float* x = (const float*)d_in[0];
  const float* c = (const float*)d_in[1];
  const float* vec = (const float*)d_in[2];
  const float* w_mod = (const float*)d_in[3];
  const float* b_mod = (const float*)d_in[4];
  const float* w_qkv_x = (const float*)d_in[5];
  const float* b_qkv_x = (const float*)d_in[6];
  const float* w_qkv_c = (const float*)d_in[7];
  const float* b_qkv_c = (const float*)d_in[8];
  const float* w_proj_x = (const float*)d_in[9];
  const float* b_proj_x = (const float*)d_in[10];
  const float* w_proj_c = (const float*)d_in[11];
  const float* b_proj_c = (const float*)d_in[12];
  const float* w1_x = (const float*)d_in[13];
  const float* b1_x = (const float*)d_in[14];
  const float* w2_x = (const float*)d_in[15];
  const float* b2_x = (const float*)d_in[16];
  const float* w1_c = (const float*)d_in[17];
  const float* b1_c = (const float*)d_in[18];
  const float* w2_c = (const float*)d_in[19];
  const float* b2_c = (const float*)d_in[20];

  if (ws_size < 229195776ull) return;  // workspace layout below needs this much

  char* ws = (char*)d_ws;
  // persistent: bf16-transposed weights + mod
  u16* wt_qkv_x = (u16*)(ws + 0);
  u16* wt_qkv_c = (u16*)(ws + 14155776);
  u16* wt_proj_x = (u16*)(ws + 28311552);
  u16* wt_proj_c = (u16*)(ws + 33030144);
  u16* wt_w1_x = (u16*)(ws + 37748736);
  u16* wt_w1_c = (u16*)(ws + 56623104);
  u16* wt_w2_x = (u16*)(ws + 75497472);
  u16* wt_w2_c = (u16*)(ws + 94371840);
  float* modf = (float*)(ws + 113246208);
  char* S = ws + 113393664;
  // slot 1 (14,475,264 B): x_n/c_n -> o_x/o_c -> xln/cln
  u16* xn = (u16*)(S);
  u16* cn = (u16*)(S + 12582912);
  // slot 2 (43,425,792 B): qkv_x_out/qkv_c_out -> x2/c2 (f32)
  u16* qkvx = (u16*)(S + 14475264);
  u16* qkvc = (u16*)(S + 52224000);
  float* x2 = (float*)(S + 14475264);
  float* c2 = (float*)(S + 39641088);
  // slot 3 (57,901,056 B): q/k/vt -> h_x/h_c ; head also used as k_mod partials
  u16* qb = (u16*)(S + 57901056);
  u16* kb = (u16*)(S + 72376320);
  u16* vtb = (u16*)(S + 86851584);
  u16* hx = (u16*)(S + 57901056);
  u16* hc = (u16*)(S + 108232704);
  float* modpart = (float*)(S + 57901056);  // 884736 B, dead before q/k/vt written

  // 1) weights -> bf16 transposed
  k_transpose<<<dim3(NQKV / 32, DD / 32), 256, 0, stream>>>(w_qkv_x, wt_qkv_x, DD, NQKV);
  k_transpose<<<dim3(NQKV / 32, DD / 32), 256, 0, stream>>>(w_qkv_c, wt_qkv_c, DD, NQKV);
  k_transpose<<<dim3(DD / 32, DD / 32), 256, 0, stream>>>(w_proj_x, wt_proj_x, DD, DD);
  k_transpose<<<dim3(DD / 32, DD / 32), 256, 0, stream>>>(w_proj_c, wt_proj_c, DD, DD);
  k_transpose<<<dim3(MHD / 32, DD / 32), 256, 0, stream>>>(w1_x, wt_w1_x, DD, MHD);
  k_transpose<<<dim3(MHD / 32, DD / 32), 256, 0, stream>>>(w1_c, wt_w1_c, DD, MHD);
  k_transpose<<<dim3(DD / 32, MHD / 32), 256, 0, stream>>>(w2_x, wt_w2_x, MHD, DD);
  k_transpose<<<dim3(DD / 32, MHD / 32), 256, 0, stream>>>(w2_c, wt_w2_c, MHD, DD);

  // 2) modulation vector (split-K, deterministic two-stage)
  k_mod_part<<<dim3(NMOD / 256, KSPL), 256, 0, stream>>>(vec, w_mod, modpart);
  k_mod_red<<<dim3(NMOD / 256), 256, 0, stream>>>(modpart, b_mod, modf);

  // 3) modulated LN -> bf16
  k_ln<<<dim3(BB * NX), 256, 0, stream>>>(x, xn, modf, 0, DD, NX);
  k_ln<<<dim3(BB * NC), 256, 0, stream>>>(c, cn, modf, 3 * DD, 4 * DD, NC);

  // 4) QKV GEMMs
  k_gemm<0><<<dim3(NQKV / 128, 32), 256, 0, stream>>>(xn, wt_qkv_x, b_qkv_x, BB * NX, NQKV, DD, qkvx, nullptr, nullptr, 0, 1);
  k_gemm<0><<<dim3(NQKV / 128, 5), 256, 0, stream>>>(cn, wt_qkv_c, b_qkv_c, BB * NC, NQKV, DD, qkvc, nullptr, nullptr, 0, 1);

  // 5) reshape to q/k (b,h,t,d) and vt (b,h,d,t)
  k_qk<<<dim3((NT * 64 + 255) / 256, HH, BB), 256, 0, stream>>>(qkvx, qkvc, qb, kb);
  k_vt<<<dim3((NT + 63) / 64, HH, BB), 256, 0, stream>>>(qkvx, qkvc, vtb);

  // 6) flash attention -> o (written into slot 1)
  k_attn<<<dim3((NT + 63) / 64, HH, BB), 256, 0, stream>>>(qb, kb, vtb, xn, cn);

  // 7) output projections with gated residual -> x2/c2 f32
  k_gemm<2><<<dim3(DD / 128, 32), 256, 0, stream>>>(xn, wt_proj_x, b_proj_x, BB * NX, DD, DD, x2, x, modf, 2 * DD, NX);
  k_gemm<2><<<dim3(DD / 128, 5), 256, 0, stream>>>(cn, wt_proj_c, b_proj_c, BB * NC, DD, DD, c2, c, modf, 5 * DD, NC);

  // 8) plain LN -> bf16
  k_ln<<<dim3(BB * NX), 256, 0, stream>>>(x2, xn, nullptr, 0, 0, NX);
  k_ln<<<dim3(BB * NC), 256, 0, stream>>>(c2, cn, nullptr, 0, 0, NC);

  // 9) MLP
  k_gemm<1><<<dim3(MHD / 128, 32), 256, 0, stream>>>(xn, wt_w1_x, b1_x, BB * NX, MHD, DD, hx, nullptr, nullptr, 0, 1);
  k_gemm<1><<<dim3(MHD / 128, 5), 256, 0, stream>>>(cn, wt_w1_c, b1_c, BB * NC, MHD, DD, hc, nullptr, nullptr, 0, 1);

  float* outx = (float*)d_out;
  float* outc = outx + (size_t)BB * NX * DD;
  k_gemm<3><<<dim3(DD / 128, 32), 256, 0, stream>>>(hx, wt_w2_x, b2_x, BB * NX, DD, MHD, outx, x2, nullptr, 0, NX);
  k_gemm<3><<<dim3(DD / 128, 5), 256, 0, stream>>>(hc, wt_w2_c, b2_c, BB * NC, DD, MHD, outc, c2, nullptr, 0, NC);
}

// Round 4
// 900.579 us; speedup vs baseline: 1.2649x; 1.1593x over previous
//
#include <hip/hip_runtime.h>
#include <stdint.h>

typedef unsigned short u16;
typedef unsigned int u32;
typedef __attribute__((ext_vector_type(8))) short bf16x8;
typedef __attribute__((ext_vector_type(8))) unsigned short u16x8;
typedef __attribute__((ext_vector_type(4))) float f32x4;

#define LB256 __launch_bounds__(256, 2)

// ---- problem dims ----
#define BB 4
#define NX 1024
#define NC 154
#define NT 1178
#define NTP 1184   // padded t stride for V^T (16B-aligned rows)
#define DD 1536
#define HH 24
#define MHD 6144
#define NQKV 4608
#define NMOD 9216
#define KSPL 6

__device__ __forceinline__ int imin(int a, int b) { return a < b ? a : b; }

__device__ __forceinline__ u16 f2bf(float f) {
  u32 u = __float_as_uint(f);
  u32 r = (u + 0x7fffu + ((u >> 16) & 1u)) >> 16;
  return (u16)r;
}

__device__ __forceinline__ float bf2f(u16 v) {
  u32 u = ((u32)v) << 16;
  return __uint_as_float(u);
}

__device__ __forceinline__ float gelu_t(float x) {
  float x2 = x * x;
  float t = tanhf(0.7978845608028654f * x * (1.f + 0.044715f * x2));
  return 0.5f * x * (1.f + t);
}

__device__ __forceinline__ f32x4 fzero4() {
  f32x4 z; z[0] = 0.f; z[1] = 0.f; z[2] = 0.f; z[3] = 0.f; return z;
}

// async global->LDS, 16B per lane; LDS dest = wave-uniform base + lane*16
__device__ __forceinline__ void glds16(const u16* g, u16* l) {
  __builtin_amdgcn_global_load_lds(
      (const __attribute__((address_space(1))) void*)g,
      (__attribute__((address_space(3))) void*)l, 16, 0, 0);
}

#define WAITV4 asm volatile("s_waitcnt vmcnt(4)" ::: "memory")
#define WAITV0 asm volatile("s_waitcnt vmcnt(0)" ::: "memory")
#define SCHEDB __builtin_amdgcn_sched_barrier(0)

// ---- weight transpose + f32->bf16: W[K][N] -> Wt[N][K] ----
__global__ void k_transpose(const float* __restrict__ W, u16* __restrict__ Wt, int K, int N) {
  __shared__ float tile[32][33];
  int n0 = blockIdx.x * 32, k0 = blockIdx.y * 32;
  int tx = threadIdx.x & 31, ty = threadIdx.x >> 5;  // 32 x 8
#pragma unroll
  for (int j = 0; j < 32; j += 8)
    tile[ty + j][tx] = W[(size_t)(k0 + ty + j) * N + n0 + tx];
  __syncthreads();
#pragma unroll
  for (int j = 0; j < 32; j += 8)
    Wt[(size_t)(n0 + ty + j) * K + k0 + tx] = f2bf(tile[tx][ty + j]);
}

// ---- mod = silu(vec) @ w_mod + b_mod : split-K partials (deterministic) ----
__global__ void k_mod_part(const float* __restrict__ vec, const float* __restrict__ w_mod,
                           float* __restrict__ part) {
  __shared__ float sv[BB][256];
  int n = blockIdx.x * 256 + threadIdx.x;
  int kb = blockIdx.y;
  int k0 = kb * 256;
  for (int i = threadIdx.x; i < BB * 256; i += 256) {
    int b = i >> 8, kk = i & 255;
    float v = vec[b * DD + k0 + kk];
    sv[b][kk] = v / (1.f + __expf(-v));
  }
  __syncthreads();
  float a0 = 0.f, a1 = 0.f, a2 = 0.f, a3 = 0.f;
  for (int k = 0; k < 256; ++k) {
    float w = w_mod[(size_t)(k0 + k) * NMOD + n];
    a0 = fmaf(sv[0][k], w, a0);
    a1 = fmaf(sv[1][k], w, a1);
    a2 = fmaf(sv[2][k], w, a2);
    a3 = fmaf(sv[3][k], w, a3);
  }
  part[((size_t)kb * BB + 0) * NMOD + n] = a0;
  part[((size_t)kb * BB + 1) * NMOD + n] = a1;
  part[((size_t)kb * BB + 2) * NMOD + n] = a2;
  part[((size_t)kb * BB + 3) * NMOD + n] = a3;
}

__global__ void k_mod_red(const float* __restrict__ part, const float* __restrict__ b_mod,
                          float* __restrict__ mod) {
  int n = blockIdx.x * 256 + threadIdx.x;
  float bb = b_mod[n];
#pragma unroll
  for (int b = 0; b < BB; ++b) {
    float s = bb;
#pragma unroll
    for (int kb = 0; kb < KSPL; ++kb) s += part[((size_t)kb * BB + b) * NMOD + n];
    mod[b * NMOD + n] = s;
  }
}

// ---- LayerNorm (optionally modulated) f32 -> bf16 ----
__global__ LB256 void k_ln(const float* __restrict__ in, u16* __restrict__ out,
                           const float* __restrict__ modp, int sh_off, int sc_off,
                           int rows_per_b) {
  int row = blockIdx.x;
  int b = row / rows_per_b;
  const float* xr = in + (size_t)row * DD;
  float v[6];
  float s = 0.f, s2 = 0.f;
#pragma unroll
  for (int i = 0; i < 6; ++i) {
    float t = xr[threadIdx.x + 256 * i];
    v[i] = t; s += t; s2 += t * t;
  }
#pragma unroll
  for (int m = 32; m >= 1; m >>= 1) {
    s += __shfl_xor(s, m);
    s2 += __shfl_xor(s2, m);
  }
  __shared__ float red[8];
  int wid = threadIdx.x >> 6;
  if ((threadIdx.x & 63) == 0) { red[wid] = s; red[4 + wid] = s2; }
  __syncthreads();
  s = red[0] + red[1] + red[2] + red[3];
  s2 = red[4] + red[5] + red[6] + red[7];
  float mean = s * (1.f / (float)DD);
  float var = s2 * (1.f / (float)DD) - mean * mean;
  float rstd = rsqrtf(var + 1e-6f);
#pragma unroll
  for (int i = 0; i < 6; ++i) {
    int d = threadIdx.x + 256 * i;
    float y = (v[i] - mean) * rstd;
    if (modp) y = y * (1.f + modp[b * NMOD + sc_off + d]) + modp[b * NMOD + sh_off + d];
    out[(size_t)row * DD + d] = f2bf(y);
  }
}

// ---- pipelined bf16 MFMA GEMM: C = A(MxK) @ Bt(NxK)^T (+bias), 128x128x32 tile
// 3-buffer LDS, counted vmcnt(4), single raw barrier per K-step, XOR-swizzled LDS.
// Swizzle: logical k-slot s of row lives at phys slot s ^ ((row>>1)&3) -> read
// lanes hit 8 distinct 16B units (2-way aliasing = free, m136).
// EPI: 0 bias->bf16 | 1 gelu(bias+acc)->bf16 | 2 resid+g*(acc+bias)->f32 |
//      3 resid+acc+bias->f32 | 4 acc->bf16 partial at outp + z*goff (split-K)
template <int EPI>
__global__ LB256 void k_gemm(const u16* __restrict__ A, const u16* __restrict__ Bt,
                             const float* __restrict__ bias, int M, int N,
                             int lda, int ldb, int kLen, int kzOff,
                             void* __restrict__ outp, const float* __restrict__ resid,
                             const float* __restrict__ modp, int goff, int rows_per_b) {
  __shared__ __align__(16) u16 sm[3 * 8192];  // 3 x (A 4096 + B 4096) u16 = 48 KB
  const int tid = threadIdx.x;
  const int lane = tid & 63;
  const int g = lane >> 4, r = lane & 15;
  const int wid = tid >> 6;

  // bijective XCD-aware tile remap (m204)
  const int gx = gridDim.x;
  const int nwg = gx * gridDim.y;
  int wg = blockIdx.y * gx + blockIdx.x;
  {
    int q = nwg >> 3, rr = nwg & 7;
    int xcd = wg & 7, sl = wg >> 3;
    wg = (xcd < rr ? xcd * (q + 1) : rr * (q + 1) + (xcd - rr) * q) + sl;
  }
  const int m0 = (wg / gx) * 128, n0 = (wg % gx) * 128;
  const int wm = (wid >> 1) * 64, wn = (wid & 1) * 64;

  A += (size_t)blockIdx.z * kzOff;
  Bt += (size_t)blockIdx.z * kzOff;

  f32x4 acc[4][4];
#pragma unroll
  for (int i = 0; i < 4; ++i)
#pragma unroll
    for (int j = 0; j < 4; ++j) acc[i][j] = fzero4();

  // staging geometry: tile (A or B) = 8 chunks of 1KB; wave wid owns chunks
  // c0=wid*2, c1=wid*2+1. lane l -> phys row c*16 + l/4, phys slot l&3.
  // phys slot s holds logical slot s ^ ((row>>1)&3); (row>>1)&3 == (l>>3)&3.
  const int rl = lane >> 2;
  const int slg = (lane & 3) ^ ((lane >> 3) & 3);
  const int c0 = wid * 2, c1 = wid * 2 + 1;
  const size_t aR0 = (size_t)imin(m0 + c0 * 16 + rl, M - 1) * lda + slg * 8;
  const size_t aR1 = (size_t)imin(m0 + c1 * 16 + rl, M - 1) * lda + slg * 8;
  const size_t bR0 = (size_t)(n0 + c0 * 16 + rl) * ldb + slg * 8;
  const size_t bR1 = (size_t)(n0 + c1 * 16 + rl) * ldb + slg * 8;

  // read-side swizzled u16 offsets: fragment row = wm+mi*16+r -> (row>>1)&3 == (r>>1)&3
  int aOff[4], bOff[4];
#pragma unroll
  for (int mi = 0; mi < 4; ++mi) aOff[mi] = (wm + mi * 16 + r) * 32 + ((g ^ ((r >> 1) & 3)) * 8);
#pragma unroll
  for (int ni = 0; ni < 4; ++ni) bOff[ni] = 4096 + (wn + ni * 16 + r) * 32 + ((g ^ ((r >> 1) & 3)) * 8);

  const int nt = kLen >> 5;  // K-steps of 32

#define STAGE(BI, T)                                        \
  do {                                                      \
    u16* bb = &sm[(BI) * 8192];                             \
    size_t kk = (size_t)(T) * 32;                           \
    glds16(A + aR0 + kk, bb + c0 * 512);                    \
    glds16(A + aR1 + kk, bb + c1 * 512);                    \
    glds16(Bt + bR0 + kk, bb + 4096 + c0 * 512);            \
    glds16(Bt + bR1 + kk, bb + 4096 + c1 * 512);            \
  } while (0)

  // prologue: tiles 0,1 -> bufs 0,1  (8 loads in flight per wave)
  STAGE(0, 0);
  STAGE(1, 1);

  for (int t = 0; t < nt - 1; ++t) {
    WAITV4;                              // my tile-t loads landed (t+1 in flight)
    __builtin_amdgcn_s_barrier();        // all waves' tile-t data published
    SCHEDB;                              // pin STAGE/ds_reads below the barrier
    if (t + 2 < nt) STAGE((t + 2) % 3, t + 2);  // overwrites tile t-1's buf (reads retired)
    const u16* bb = &sm[(t % 3) * 8192];
    bf16x8 af[4], bfr[4];
#pragma unroll
    for (int mi = 0; mi < 4; ++mi) af[mi] = *(const bf16x8*)(bb + aOff[mi]);
#pragma unroll
    for (int ni = 0; ni < 4; ++ni) bfr[ni] = *(const bf16x8*)(bb + bOff[ni]);
    __builtin_amdgcn_s_setprio(1);
#pragma unroll
    for (int mi = 0; mi < 4; ++mi)
#pragma unroll
      for (int ni = 0; ni < 4; ++ni)
        acc[mi][ni] = __builtin_amdgcn_mfma_f32_16x16x32_bf16(af[mi], bfr[ni], acc[mi][ni], 0, 0, 0);
    __builtin_amdgcn_s_setprio(0);
    SCHEDB;                              // pin this iteration's body before next WAITV
  }
  // tail iteration
  {
    WAITV0;
    __builtin_amdgcn_s_barrier();
    SCHEDB;
    const u16* bb = &sm[((nt - 1) % 3) * 8192];
    bf16x8 af[4], bfr[4];
#pragma unroll
    for (int mi = 0; mi < 4; ++mi) af[mi] = *(const bf16x8*)(bb + aOff[mi]);
#pragma unroll
    for (int ni = 0; ni < 4; ++ni) bfr[ni] = *(const bf16x8*)(bb + bOff[ni]);
#pragma unroll
    for (int mi = 0; mi < 4; ++mi)
#pragma unroll
      for (int ni = 0; ni < 4; ++ni)
        acc[mi][ni] = __builtin_amdgcn_mfma_f32_16x16x32_bf16(af[mi], bfr[ni], acc[mi][ni], 0, 0, 0);
  }
#undef STAGE

#pragma unroll
  for (int mi = 0; mi < 4; ++mi) {
#pragma unroll
    for (int ni = 0; ni < 4; ++ni) {
      const int col = n0 + wn + ni * 16 + r;
      float bv = 0.f;
      if constexpr (EPI != 4) bv = bias[col];
#pragma unroll
      for (int j = 0; j < 4; ++j) {
        const int row = m0 + wm + mi * 16 + g * 4 + j;
        if (row >= M) continue;
        const size_t off = (size_t)row * N + col;
        if constexpr (EPI == 0) {
          ((u16*)outp)[off] = f2bf(acc[mi][ni][j] + bv);
        } else if constexpr (EPI == 1) {
          ((u16*)outp)[off] = f2bf(gelu_t(acc[mi][ni][j] + bv));
        } else if constexpr (EPI == 2) {
          const int b = row / rows_per_b;
          ((float*)outp)[off] = resid[off] + modp[b * NMOD + goff + col] * (acc[mi][ni][j] + bv);
        } else if constexpr (EPI == 3) {
          ((float*)outp)[off] = resid[off] + acc[mi][ni][j] + bv;
        } else {
          ((u16*)outp)[(size_t)blockIdx.z * (size_t)goff + off] = f2bf(acc[mi][ni][j]);
        }
      }
    }
  }
}

// ---- split-K reduce for mlp2_x: out = resid + bias + p0 + p1 ----
__global__ void k_red(const u16* __restrict__ p0, const u16* __restrict__ p1,
                      const float* __restrict__ resid, const float* __restrict__ bias,
                      float* __restrict__ out) {
  size_t base = (size_t)blockIdx.x * DD;
#pragma unroll
  for (int i = 0; i < 6; ++i) {
    int j = threadIdx.x + 256 * i;
    out[base + j] = resid[base + j] + bias[j] + bf2f(p0[base + j]) + bf2f(p1[base + j]);
  }
}

// ---- scatter qkv GEMM output into q,k (b,h,t,d) bf16 ----
__global__ void k_qk(const u16* __restrict__ qkvx, const u16* __restrict__ qkvc,
                     u16* __restrict__ q, u16* __restrict__ k) {
  int idx = blockIdx.x * 256 + threadIdx.x;
  if (idx >= NT * 64) return;
  int t = idx >> 6, d = idx & 63;
  int h = blockIdx.y, b = blockIdx.z;
  const u16* src = (t < NX) ? qkvx + (size_t)(b * NX + t) * NQKV
                            : qkvc + (size_t)(b * NC + t - NX) * NQKV;
  size_t o = ((size_t)(b * HH + h) * NT + t) * 64 + d;
  q[o] = src[h * 64 + d];
  k[o] = src[DD + h * 64 + d];
}

// ---- V transpose: qkv v-cols -> vt (b,h,d,t) bf16, t-stride NTP ----
__global__ void k_vt(const u16* __restrict__ qkvx, const u16* __restrict__ qkvc,
                     u16* __restrict__ vt) {
  __shared__ u16 tile[64][65];
  int t0 = blockIdx.x * 64;
  int h = blockIdx.y, b = blockIdx.z;
  int tx = threadIdx.x & 63, ty = threadIdx.x >> 6;
#pragma unroll
  for (int j = 0; j < 16; ++j) {
    int tt = ty * 16 + j;
    int t = t0 + tt;
    if (t < NT) {
      const u16* src = (t < NX) ? qkvx + (size_t)(b * NX + t) * NQKV
                                : qkvc + (size_t)(b * NC + t - NX) * NQKV;
      tile[tt][tx] = src[2 * DD + h * 64 + tx];
    }
  }
  __syncthreads();
  size_t base = (size_t)(b * HH + h) * 64 * NTP;
#pragma unroll
  for (int j = 0; j < 16; ++j) {
    int dd = ty * 16 + j;
    int t = t0 + tx;
    if (t < NT) vt[base + (size_t)dd * NTP + t] = tile[tx][dd];
  }
}

// ---- flash attention: QBLK=64 (4 waves x 16 rows), KBLK=64, HD=64 ----
__global__ LB256 void k_attn(const u16* __restrict__ q, const u16* __restrict__ kk,
                             const u16* __restrict__ vt, u16* __restrict__ ox,
                             u16* __restrict__ oc) {
  __shared__ __align__(16) u16 Ks[64][72];
  __shared__ __align__(16) u16 Vs[64][72];
  __shared__ __align__(16) u16 Ps[4][16][72];

  const int lane = threadIdx.x & 63, wid = threadIdx.x >> 6;
  const int g = lane >> 4, r = lane & 15;
  const int q0 = blockIdx.x * 64;
  const int h = blockIdx.y, b = blockIdx.z;
  const size_t bh = (size_t)b * HH + h;
  const u16* qp = q + bh * (NT * 64);
  const u16* kp = kk + bh * (NT * 64);
  const u16* vp = vt + bh * (64 * NTP);

  const int qrow = imin(q0 + wid * 16 + r, NT - 1);
  const bf16x8 qa0 = *(const bf16x8*)(qp + (size_t)qrow * 64 + g * 8);
  const bf16x8 qa1 = *(const bf16x8*)(qp + (size_t)qrow * 64 + 32 + g * 8);

  f32x4 oacc[4];
#pragma unroll
  for (int i = 0; i < 4; ++i) oacc[i] = fzero4();
  float mrow[4], lrow[4];
#pragma unroll
  for (int j = 0; j < 4; ++j) { mrow[j] = -1e30f; lrow[j] = 0.f; }

  for (int t0 = 0; t0 < NT; t0 += 64) {
    u16x8 kreg[2], vreg[2];
    int tr0[2], cc0[2];
#pragma unroll
    for (int p = 0; p < 2; ++p) {
      int chunk = p * 256 + threadIdx.x;
      tr0[p] = chunk >> 3;
      cc0[p] = (chunk & 7) * 8;
      int tsrc = imin(t0 + tr0[p], NT - 1);
      kreg[p] = *(const u16x8*)(kp + (size_t)tsrc * 64 + cc0[p]);
      int tcol = t0 + cc0[p];
      if (tcol + 8 <= NT) {
        vreg[p] = *(const u16x8*)(vp + (size_t)tr0[p] * NTP + tcol);
      } else {
#pragma unroll
        for (int e = 0; e < 8; ++e)
          vreg[p][e] = vp[(size_t)tr0[p] * NTP + imin(tcol + e, NT - 1)];
      }
    }
    __syncthreads();
#pragma unroll
    for (int p = 0; p < 2; ++p) {
      *(u16x8*)&Ks[tr0[p]][cc0[p]] = kreg[p];
      *(u16x8*)&Vs[tr0[p]][cc0[p]] = vreg[p];
    }
    __syncthreads();

    // S = Q K^T * scale
    f32x4 s[4];
#pragma unroll
    for (int ni = 0; ni < 4; ++ni) {
      s[ni] = fzero4();
      s[ni] = __builtin_amdgcn_mfma_f32_16x16x32_bf16(qa0, *(const bf16x8*)&Ks[ni * 16 + r][g * 8], s[ni], 0, 0, 0);
      s[ni] = __builtin_amdgcn_mfma_f32_16x16x32_bf16(qa1, *(const bf16x8*)&Ks[ni * 16 + r][32 + g * 8], s[ni], 0, 0, 0);
    }

    float pv[4][4], pm[4];
#pragma unroll
    for (int j = 0; j < 4; ++j) pm[j] = -1e30f;
#pragma unroll
    for (int ni = 0; ni < 4; ++ni) {
      int tcol = t0 + ni * 16 + r;
      bool ok = tcol < NT;
#pragma unroll
      for (int j = 0; j < 4; ++j) {
        float sv = ok ? s[ni][j] * 0.125f : -1e30f;
        pv[ni][j] = sv;
        pm[j] = fmaxf(pm[j], sv);
      }
    }
#pragma unroll
    for (int j = 0; j < 4; ++j) {
#pragma unroll
      for (int msk = 1; msk <= 8; msk <<= 1) pm[j] = fmaxf(pm[j], __shfl_xor(pm[j], msk));
    }
    float alpha[4], rs[4];
#pragma unroll
    for (int j = 0; j < 4; ++j) {
      float mn = fmaxf(mrow[j], pm[j]);
      alpha[j] = __expf(mrow[j] - mn);
      mrow[j] = mn;
      rs[j] = 0.f;
    }
#pragma unroll
    for (int ni = 0; ni < 4; ++ni)
#pragma unroll
      for (int j = 0; j < 4; ++j) {
        float p = __expf(pv[ni][j] - mrow[j]);
        pv[ni][j] = p;
        rs[j] += p;
      }
#pragma unroll
    for (int j = 0; j < 4; ++j) {
#pragma unroll
      for (int msk = 1; msk <= 8; msk <<= 1) rs[j] += __shfl_xor(rs[j], msk);
      lrow[j] = lrow[j] * alpha[j] + rs[j];
    }
#pragma unroll
    for (int ni = 0; ni < 4; ++ni)
#pragma unroll
      for (int j = 0; j < 4; ++j) oacc[ni][j] *= alpha[j];

    // P -> per-wave LDS (bf16), re-read as A fragment
#pragma unroll
    for (int ni = 0; ni < 4; ++ni)
#pragma unroll
      for (int j = 0; j < 4; ++j)
        Ps[wid][g * 4 + j][ni * 16 + r] = f2bf(pv[ni][j]);

    bf16x8 pa0 = *(const bf16x8*)&Ps[wid][r][g * 8];
    bf16x8 pa1 = *(const bf16x8*)&Ps[wid][r][32 + g * 8];
#pragma unroll
    for (int ni = 0; ni < 4; ++ni) {
      oacc[ni] = __builtin_amdgcn_mfma_f32_16x16x32_bf16(pa0, *(const bf16x8*)&Vs[ni * 16 + r][g * 8], oacc[ni], 0, 0, 0);
      oacc[ni] = __builtin_amdgcn_mfma_f32_16x16x32_bf16(pa1, *(const bf16x8*)&Vs[ni * 16 + r][32 + g * 8], oacc[ni], 0, 0, 0);
    }
  }

#pragma unroll
  for (int ni = 0; ni < 4; ++ni)
#pragma unroll
    for (int j = 0; j < 4; ++j) {
      int tq = q0 + wid * 16 + g * 4 + j;
      if (tq >= NT) continue;
      float val = oacc[ni][j] / lrow[j];
      int col = h * 64 + ni * 16 + r;
      if (tq < NX)
        ox[(size_t)(b * NX + tq) * DD + col] = f2bf(val);
      else
        oc[(size_t)(b * NC + tq - NX) * DD + col] = f2bf(val);
    }
}

extern "C" void kernel_launch(void* const* d_in, const int* in_sizes, int n_in,
                              void* d_out, int out_size, void* d_ws, size_t ws_size,
                              hipStream_t stream) {
  const float* x = (const float*)d_in[0];
  const float* c = (const float*)d_in[1];
  const float* vec = (const float*)d_in[2];
  const float* w_mod = (const float*)d_in[3];
  const float* b_mod = (const float*)d_in[4];
  const float* w_qkv_x = (const float*)d_in[5];
  const float* b_qkv_x = (const float*)d_in[6];
  const float* w_qkv_c = (const float*)d_in[7];
  const float* b_qkv_c = (const float*)d_in[8];
  const float* w_proj_x = (const float*)d_in[9];
  const float* b_proj_x = (const float*)d_in[10];
  const float* w_proj_c = (const float*)d_in[11];
  const float* b_proj_c = (const float*)d_in[12];
  const float* w1_x = (const float*)d_in[13];
  const float* b1_x = (const float*)d_in[14];
  const float* w2_x = (const float*)d_in[15];
  const float* b2_x = (const float*)d_in[16];
  const float* w1_c = (const float*)d_in[17];
  const float* b1_c = (const float*)d_in[18];
  const float* w2_c = (const float*)d_in[19];
  const float* b2_c = (const float*)d_in[20];

  if (ws_size < 229195776ull) return;  // workspace layout below needs this much

  char* ws = (char*)d_ws;
  // persistent: bf16-transposed weights + mod
  u16* wt_qkv_x = (u16*)(ws + 0);
  u16* wt_qkv_c = (u16*)(ws + 14155776);
  u16* wt_proj_x = (u16*)(ws + 28311552);
  u16* wt_proj_c = (u16*)(ws + 33030144);
  u16* wt_w1_x = (u16*)(ws + 37748736);
  u16* wt_w1_c = (u16*)(ws + 56623104);
  u16* wt_w2_x = (u16*)(ws + 75497472);
  u16* wt_w2_c = (u16*)(ws + 94371840);
  float* modf = (float*)(ws + 113246208);
  char* S = ws + 113393664;
  // slot 1 (14,475,264 B): x_n/c_n -> o_x/o_c -> xln/cln -> pb0 (mlp2 partial z=0)
  u16* xn = (u16*)(S);
  u16* cn = (u16*)(S + 12582912);
  // slot 2 (43,425,792 B): qkv_x_out/qkv_c_out -> x2/c2 (f32)
  u16* qkvx = (u16*)(S + 14475264);
  u16* qkvc = (u16*)(S + 52224000);
  float* x2 = (float*)(S + 14475264);   // 25,165,824 B, ends S+39,641,088
  float* c2 = (float*)(S + 39641088);   //  3,784,704 B, ends S+43,425,792
  u16* pb0 = (u16*)(S);                 // 12,582,912 B (xn/cn dead after mlp1 reads)
  u16* pb1 = (u16*)(S + 43425792);      // 12,582,912 B (qkv outputs dead, after c2)
  // partial stride pb0 -> pb1 in u16 elements:
  const int PSTRIDE = 43425792 / 2;     // 21,712,896
  // slot 3 (57,901,056 B): q/k/vt -> h_x/h_c ; head also used as k_mod partials
  u16* qb = (u16*)(S + 57901056);
  u16* kb = (u16*)(S + 72376320);
  u16* vtb = (u16*)(S + 86851584);
  u16* hx = (u16*)(S + 57901056);
  u16* hc = (u16*)(S + 108232704);
  float* modpart = (float*)(S + 57901056);  // 884736 B, dead before q/k/vt written

  // 1) weights -> bf16 transposed
  k_transpose<<<dim3(NQKV / 32, DD / 32), 256, 0, stream>>>(w_qkv_x, wt_qkv_x, DD, NQKV);
  k_transpose<<<dim3(NQKV / 32, DD / 32), 256, 0, stream>>>(w_qkv_c, wt_qkv_c, DD, NQKV);
  k_transpose<<<dim3(DD / 32, DD / 32), 256, 0, stream>>>(w_proj_x, wt_proj_x, DD, DD);
  k_transpose<<<dim3(DD / 32, DD / 32), 256, 0, stream>>>(w_proj_c, wt_proj_c, DD, DD);
  k_transpose<<<dim3(MHD / 32, DD / 32), 256, 0, stream>>>(w1_x, wt_w1_x, DD, MHD);
  k_transpose<<<dim3(MHD / 32, DD / 32), 256, 0, stream>>>(w1_c, wt_w1_c, DD, MHD);
  k_transpose<<<dim3(DD / 32, MHD / 32), 256, 0, stream>>>(w2_x, wt_w2_x, MHD, DD);
  k_transpose<<<dim3(DD / 32, MHD / 32), 256, 0, stream>>>(w2_c, wt_w2_c, MHD, DD);

  // 2) modulation vector (split-K, deterministic two-stage)
  k_mod_part<<<dim3(NMOD / 256, KSPL), 256, 0, stream>>>(vec, w_mod, modpart);
  k_mod_red<<<dim3(NMOD / 256), 256, 0, stream>>>(modpart, b_mod, modf);

  // 3) modulated LN -> bf16
  k_ln<<<dim3(BB * NX), 256, 0, stream>>>(x, xn, modf, 0, DD, NX);
  k_ln<<<dim3(BB * NC), 256, 0, stream>>>(c, cn, modf, 3 * DD, 4 * DD, NC);

  // 4) QKV GEMMs
  k_gemm<0><<<dim3(NQKV / 128, 32), 256, 0, stream>>>(xn, wt_qkv_x, b_qkv_x, BB * NX, NQKV, DD, DD, DD, 0, qkvx, nullptr, nullptr, 0, 1);
  k_gemm<0><<<dim3(NQKV / 128, 5), 256, 0, stream>>>(cn, wt_qkv_c, b_qkv_c, BB * NC, NQKV, DD, DD, DD, 0, qkvc, nullptr, nullptr, 0, 1);

  // 5) reshape to q/k (b,h,t,d) and vt (b,h,d,t)
  k_qk<<<dim3((NT * 64 + 255) / 256, HH, BB), 256, 0, stream>>>(qkvx, qkvc, qb, kb);
  k_vt<<<dim3((NT + 63) / 64, HH, BB), 256, 0, stream>>>(qkvx, qkvc, vtb);

  // 6) flash attention -> o (written into slot 1)
  k_attn<<<dim3((NT + 63) / 64, HH, BB), 256, 0, stream>>>(qb, kb, vtb, xn, cn);

  // 7) output projections with gated residual -> x2/c2 f32
  k_gemm<2><<<dim3(DD / 128, 32), 256, 0, stream>>>(xn, wt_proj_x, b_proj_x, BB * NX, DD, DD, DD, DD, 0, x2, x, modf, 2 * DD, NX);
  k_gemm<2><<<dim3(DD / 128, 5), 256, 0, stream>>>(cn, wt_proj_c, b_proj_c, BB * NC, DD, DD, DD, DD, 0, c2, c, modf, 5 * DD, NC);

  // 8) plain LN -> bf16
  k_ln<<<dim3(BB * NX), 256, 0, stream>>>(x2, xn, nullptr, 0, 0, NX);
  k_ln<<<dim3(BB * NC), 256, 0, stream>>>(c2, cn, nullptr, 0, 0, NC);

  // 9) MLP
  k_gemm<1><<<dim3(MHD / 128, 32), 256, 0, stream>>>(xn, wt_w1_x, b1_x, BB * NX, MHD, DD, DD, DD, 0, hx, nullptr, nullptr, 0, 1);
  k_gemm<1><<<dim3(MHD / 128, 5), 256, 0, stream>>>(cn, wt_w1_c, b1_c, BB * NC, MHD, DD, DD, DD, 0, hc, nullptr, nullptr, 0, 1);

  float* outx = (float*)d_out;
  float* outc = outx + (size_t)BB * NX * DD;
  // mlp2_x: concurrent split-K (z=0: K[0,3072), z=1: K[3072,6144)) -> bf16
  // partials at pb0 / pb0 + PSTRIDE (== pb1, disjoint from live x2/c2) -> reduce
  k_gemm<4><<<dim3(DD / 128, 32, 2), 256, 0, stream>>>(hx, wt_w2_x, b2_x, BB * NX, DD, MHD, MHD, MHD / 2, MHD / 2, pb0, nullptr, nullptr, PSTRIDE, NX);
  k_red<<<dim3(BB * NX), 256, 0, stream>>>(pb0, pb1, x2, b2_x, outx);
  k_gemm<3><<<dim3(DD / 128, 5), 256, 0, stream>>>(hc, wt_w2_c, b2_c, BB * NC, DD, MHD, MHD, MHD, 0, outc, c2, nullptr, 0, NC);
}

// Round 5
// 863.957 us; speedup vs baseline: 1.3185x; 1.0424x over previous
//
#include <hip/hip_runtime.h>
#include <stdint.h>

typedef unsigned short u16;
typedef unsigned int u32;
typedef __attribute__((ext_vector_type(8))) short bf16x8;
typedef __attribute__((ext_vector_type(8))) unsigned short u16x8;
typedef __attribute__((ext_vector_type(2))) unsigned int u32x2;
typedef __attribute__((ext_vector_type(4))) float f32x4;

#define LB256 __launch_bounds__(256, 2)

// ---- problem dims ----
#define BB 4
#define NX 1024
#define NC 154
#define NT 1178
#define NTP 1184   // padded t stride for V^T (16B-aligned rows)
#define DD 1536
#define HH 24
#define MHD 6144
#define NQKV 4608
#define NMOD 9216
#define KSPL 6

__device__ __forceinline__ int imin(int a, int b) { return a < b ? a : b; }

__device__ __forceinline__ u16 f2bf(float f) {
  u32 u = __float_as_uint(f);
  u32 r = (u + 0x7fffu + ((u >> 16) & 1u)) >> 16;
  return (u16)r;
}

__device__ __forceinline__ float bf2f(u16 v) {
  u32 u = ((u32)v) << 16;
  return __uint_as_float(u);
}

__device__ __forceinline__ float gelu_t(float x) {
  float x2 = x * x;
  float t = tanhf(0.7978845608028654f * x * (1.f + 0.044715f * x2));
  return 0.5f * x * (1.f + t);
}

__device__ __forceinline__ f32x4 fzero4() {
  f32x4 z; z[0] = 0.f; z[1] = 0.f; z[2] = 0.f; z[3] = 0.f; return z;
}

// async global->LDS, 16B per lane; LDS dest = wave-uniform base + lane*16
__device__ __forceinline__ void glds16(const u16* g, u16* l) {
  __builtin_amdgcn_global_load_lds(
      (const __attribute__((address_space(1))) void*)g,
      (__attribute__((address_space(3))) void*)l, 16, 0, 0);
}

#define WAITV4 asm volatile("s_waitcnt vmcnt(4)" ::: "memory")
#define WAITV0 asm volatile("s_waitcnt vmcnt(0)" ::: "memory")
#define SCHEDB __builtin_amdgcn_sched_barrier(0)

// ---- weight transpose + f32->bf16: W[K][N] -> Wt[N][K] ----
__global__ void k_transpose(const float* __restrict__ W, u16* __restrict__ Wt, int K, int N) {
  __shared__ float tile[32][33];
  int n0 = blockIdx.x * 32, k0 = blockIdx.y * 32;
  int tx = threadIdx.x & 31, ty = threadIdx.x >> 5;  // 32 x 8
#pragma unroll
  for (int j = 0; j < 32; j += 8)
    tile[ty + j][tx] = W[(size_t)(k0 + ty + j) * N + n0 + tx];
  __syncthreads();
#pragma unroll
  for (int j = 0; j < 32; j += 8)
    Wt[(size_t)(n0 + ty + j) * K + k0 + tx] = f2bf(tile[tx][ty + j]);
}

// ---- mod = silu(vec) @ w_mod + b_mod : split-K partials (deterministic) ----
__global__ void k_mod_part(const float* __restrict__ vec, const float* __restrict__ w_mod,
                           float* __restrict__ part) {
  __shared__ float sv[BB][256];
  int n = blockIdx.x * 256 + threadIdx.x;
  int kb = blockIdx.y;
  int k0 = kb * 256;
  for (int i = threadIdx.x; i < BB * 256; i += 256) {
    int b = i >> 8, kk = i & 255;
    float v = vec[b * DD + k0 + kk];
    sv[b][kk] = v / (1.f + __expf(-v));
  }
  __syncthreads();
  float a0 = 0.f, a1 = 0.f, a2 = 0.f, a3 = 0.f;
  for (int k = 0; k < 256; ++k) {
    float w = w_mod[(size_t)(k0 + k) * NMOD + n];
    a0 = fmaf(sv[0][k], w, a0);
    a1 = fmaf(sv[1][k], w, a1);
    a2 = fmaf(sv[2][k], w, a2);
    a3 = fmaf(sv[3][k], w, a3);
  }
  part[((size_t)kb * BB + 0) * NMOD + n] = a0;
  part[((size_t)kb * BB + 1) * NMOD + n] = a1;
  part[((size_t)kb * BB + 2) * NMOD + n] = a2;
  part[((size_t)kb * BB + 3) * NMOD + n] = a3;
}

__global__ void k_mod_red(const float* __restrict__ part, const float* __restrict__ b_mod,
                          float* __restrict__ mod) {
  int n = blockIdx.x * 256 + threadIdx.x;
  float bb = b_mod[n];
#pragma unroll
  for (int b = 0; b < BB; ++b) {
    float s = bb;
#pragma unroll
    for (int kb = 0; kb < KSPL; ++kb) s += part[((size_t)kb * BB + b) * NMOD + n];
    mod[b * NMOD + n] = s;
  }
}

// ---- LayerNorm (optionally modulated) f32 -> bf16 ----
__global__ LB256 void k_ln(const float* __restrict__ in, u16* __restrict__ out,
                           const float* __restrict__ modp, int sh_off, int sc_off,
                           int rows_per_b) {
  int row = blockIdx.x;
  int b = row / rows_per_b;
  const float* xr = in + (size_t)row * DD;
  float v[6];
  float s = 0.f, s2 = 0.f;
#pragma unroll
  for (int i = 0; i < 6; ++i) {
    float t = xr[threadIdx.x + 256 * i];
    v[i] = t; s += t; s2 += t * t;
  }
#pragma unroll
  for (int m = 32; m >= 1; m >>= 1) {
    s += __shfl_xor(s, m);
    s2 += __shfl_xor(s2, m);
  }
  __shared__ float red[8];
  int wid = threadIdx.x >> 6;
  if ((threadIdx.x & 63) == 0) { red[wid] = s; red[4 + wid] = s2; }
  __syncthreads();
  s = red[0] + red[1] + red[2] + red[3];
  s2 = red[4] + red[5] + red[6] + red[7];
  float mean = s * (1.f / (float)DD);
  float var = s2 * (1.f / (float)DD) - mean * mean;
  float rstd = rsqrtf(var + 1e-6f);
#pragma unroll
  for (int i = 0; i < 6; ++i) {
    int d = threadIdx.x + 256 * i;
    float y = (v[i] - mean) * rstd;
    if (modp) y = y * (1.f + modp[b * NMOD + sc_off + d]) + modp[b * NMOD + sh_off + d];
    out[(size_t)row * DD + d] = f2bf(y);
  }
}

// ---- pipelined bf16 MFMA GEMM: C = A(MxK) @ Bt(NxK)^T (+bias), 128x128x32 tile
// 3-buffer LDS, counted vmcnt(4), single raw barrier per K-step, XOR-swizzled LDS.
// EPI: 0 bias->bf16 | 1 gelu(bias+acc)->bf16 | 2 resid+g*(acc+bias)->f32 |
//      3 resid+acc+bias->f32 | 4 acc->bf16 partial at outp + z*goff (split-K)
template <int EPI>
__global__ LB256 void k_gemm(const u16* __restrict__ A, const u16* __restrict__ Bt,
                             const float* __restrict__ bias, int M, int N,
                             int lda, int ldb, int kLen, int kzOff,
                             void* __restrict__ outp, const float* __restrict__ resid,
                             const float* __restrict__ modp, int goff, int rows_per_b) {
  __shared__ __align__(16) u16 sm[3 * 8192];  // 3 x (A 4096 + B 4096) u16 = 48 KB
  const int tid = threadIdx.x;
  const int lane = tid & 63;
  const int g = lane >> 4, r = lane & 15;
  const int wid = tid >> 6;

  // bijective XCD-aware tile remap (m204)
  const int gx = gridDim.x;
  const int nwg = gx * gridDim.y;
  int wg = blockIdx.y * gx + blockIdx.x;
  {
    int q = nwg >> 3, rr = nwg & 7;
    int xcd = wg & 7, sl = wg >> 3;
    wg = (xcd < rr ? xcd * (q + 1) : rr * (q + 1) + (xcd - rr) * q) + sl;
  }
  const int m0 = (wg / gx) * 128, n0 = (wg % gx) * 128;
  const int wm = (wid >> 1) * 64, wn = (wid & 1) * 64;

  A += (size_t)blockIdx.z * kzOff;
  Bt += (size_t)blockIdx.z * kzOff;

  f32x4 acc[4][4];
#pragma unroll
  for (int i = 0; i < 4; ++i)
#pragma unroll
    for (int j = 0; j < 4; ++j) acc[i][j] = fzero4();

  // staging geometry: tile (A or B) = 8 chunks of 1KB; wave wid owns chunks
  // c0=wid*2, c1=wid*2+1. lane l -> phys row c*16 + l/4, phys slot l&3.
  // phys slot s holds logical slot s ^ ((row>>1)&3); (row>>1)&3 == (l>>3)&3.
  const int rl = lane >> 2;
  const int slg = (lane & 3) ^ ((lane >> 3) & 3);
  const int c0 = wid * 2, c1 = wid * 2 + 1;
  const size_t aR0 = (size_t)imin(m0 + c0 * 16 + rl, M - 1) * lda + slg * 8;
  const size_t aR1 = (size_t)imin(m0 + c1 * 16 + rl, M - 1) * lda + slg * 8;
  const size_t bR0 = (size_t)(n0 + c0 * 16 + rl) * ldb + slg * 8;
  const size_t bR1 = (size_t)(n0 + c1 * 16 + rl) * ldb + slg * 8;

  // read-side swizzled u16 offsets: fragment row = wm+mi*16+r -> (row>>1)&3 == (r>>1)&3
  int aOff[4], bOff[4];
#pragma unroll
  for (int mi = 0; mi < 4; ++mi) aOff[mi] = (wm + mi * 16 + r) * 32 + ((g ^ ((r >> 1) & 3)) * 8);
#pragma unroll
  for (int ni = 0; ni < 4; ++ni) bOff[ni] = 4096 + (wn + ni * 16 + r) * 32 + ((g ^ ((r >> 1) & 3)) * 8);

  const int nt = kLen >> 5;  // K-steps of 32

#define STAGE(BI, T)                                        \
  do {                                                      \
    u16* bb = &sm[(BI) * 8192];                             \
    size_t kk = (size_t)(T) * 32;                           \
    glds16(A + aR0 + kk, bb + c0 * 512);                    \
    glds16(A + aR1 + kk, bb + c1 * 512);                    \
    glds16(Bt + bR0 + kk, bb + 4096 + c0 * 512);            \
    glds16(Bt + bR1 + kk, bb + 4096 + c1 * 512);            \
  } while (0)

  // prologue: tiles 0,1 -> bufs 0,1  (8 loads in flight per wave)
  STAGE(0, 0);
  STAGE(1, 1);

  for (int t = 0; t < nt - 1; ++t) {
    WAITV4;                              // my tile-t loads landed (t+1 in flight)
    __builtin_amdgcn_s_barrier();        // all waves' tile-t data published
    SCHEDB;                              // pin STAGE/ds_reads below the barrier
    if (t + 2 < nt) STAGE((t + 2) % 3, t + 2);  // overwrites tile t-1's buf (reads retired)
    const u16* bb = &sm[(t % 3) * 8192];
    bf16x8 af[4], bfr[4];
#pragma unroll
    for (int mi = 0; mi < 4; ++mi) af[mi] = *(const bf16x8*)(bb + aOff[mi]);
#pragma unroll
    for (int ni = 0; ni < 4; ++ni) bfr[ni] = *(const bf16x8*)(bb + bOff[ni]);
    __builtin_amdgcn_s_setprio(1);
#pragma unroll
    for (int mi = 0; mi < 4; ++mi)
#pragma unroll
      for (int ni = 0; ni < 4; ++ni)
        acc[mi][ni] = __builtin_amdgcn_mfma_f32_16x16x32_bf16(af[mi], bfr[ni], acc[mi][ni], 0, 0, 0);
    __builtin_amdgcn_s_setprio(0);
    SCHEDB;                              // pin this iteration's body before next WAITV
  }
  // tail iteration
  {
    WAITV0;
    __builtin_amdgcn_s_barrier();
    SCHEDB;
    const u16* bb = &sm[((nt - 1) % 3) * 8192];
    bf16x8 af[4], bfr[4];
#pragma unroll
    for (int mi = 0; mi < 4; ++mi) af[mi] = *(const bf16x8*)(bb + aOff[mi]);
#pragma unroll
    for (int ni = 0; ni < 4; ++ni) bfr[ni] = *(const bf16x8*)(bb + bOff[ni]);
#pragma unroll
    for (int mi = 0; mi < 4; ++mi)
#pragma unroll
      for (int ni = 0; ni < 4; ++ni)
        acc[mi][ni] = __builtin_amdgcn_mfma_f32_16x16x32_bf16(af[mi], bfr[ni], acc[mi][ni], 0, 0, 0);
  }
#undef STAGE

#pragma unroll
  for (int mi = 0; mi < 4; ++mi) {
#pragma unroll
    for (int ni = 0; ni < 4; ++ni) {
      const int col = n0 + wn + ni * 16 + r;
      float bv = 0.f;
      if constexpr (EPI != 4) bv = bias[col];
#pragma unroll
      for (int j = 0; j < 4; ++j) {
        const int row = m0 + wm + mi * 16 + g * 4 + j;
        if (row >= M) continue;
        const size_t off = (size_t)row * N + col;
        if constexpr (EPI == 0) {
          ((u16*)outp)[off] = f2bf(acc[mi][ni][j] + bv);
        } else if constexpr (EPI == 1) {
          ((u16*)outp)[off] = f2bf(gelu_t(acc[mi][ni][j] + bv));
        } else if constexpr (EPI == 2) {
          const int b = row / rows_per_b;
          ((float*)outp)[off] = resid[off] + modp[b * NMOD + goff + col] * (acc[mi][ni][j] + bv);
        } else if constexpr (EPI == 3) {
          ((float*)outp)[off] = resid[off] + acc[mi][ni][j] + bv;
        } else {
          ((u16*)outp)[(size_t)blockIdx.z * (size_t)goff + off] = f2bf(acc[mi][ni][j]);
        }
      }
    }
  }
}

// ---- split-K reduce for mlp2_x: out = resid + bias + p0 + p1 ----
__global__ void k_red(const u16* __restrict__ p0, const u16* __restrict__ p1,
                      const float* __restrict__ resid, const float* __restrict__ bias,
                      float* __restrict__ out) {
  size_t base = (size_t)blockIdx.x * DD;
#pragma unroll
  for (int i = 0; i < 6; ++i) {
    int j = threadIdx.x + 256 * i;
    out[base + j] = resid[base + j] + bias[j] + bf2f(p0[base + j]) + bf2f(p1[base + j]);
  }
}

// ---- scatter qkv GEMM output into q,k (b,h,t,d) bf16 ----
__global__ void k_qk(const u16* __restrict__ qkvx, const u16* __restrict__ qkvc,
                     u16* __restrict__ q, u16* __restrict__ k) {
  int idx = blockIdx.x * 256 + threadIdx.x;
  if (idx >= NT * 64) return;
  int t = idx >> 6, d = idx & 63;
  int h = blockIdx.y, b = blockIdx.z;
  const u16* src = (t < NX) ? qkvx + (size_t)(b * NX + t) * NQKV
                            : qkvc + (size_t)(b * NC + t - NX) * NQKV;
  size_t o = ((size_t)(b * HH + h) * NT + t) * 64 + d;
  q[o] = src[h * 64 + d];
  k[o] = src[DD + h * 64 + d];
}

// ---- V transpose: qkv v-cols -> vt (b,h,d,t) bf16, t-stride NTP ----
__global__ void k_vt(const u16* __restrict__ qkvx, const u16* __restrict__ qkvc,
                     u16* __restrict__ vt) {
  __shared__ u16 tile[64][65];
  int t0 = blockIdx.x * 64;
  int h = blockIdx.y, b = blockIdx.z;
  int tx = threadIdx.x & 63, ty = threadIdx.x >> 6;
#pragma unroll
  for (int j = 0; j < 16; ++j) {
    int tt = ty * 16 + j;
    int t = t0 + tt;
    if (t < NT) {
      const u16* src = (t < NX) ? qkvx + (size_t)(b * NX + t) * NQKV
                                : qkvc + (size_t)(b * NC + t - NX) * NQKV;
      tile[tt][tx] = src[2 * DD + h * 64 + tx];
    }
  }
  __syncthreads();
  size_t base = (size_t)(b * HH + h) * 64 * NTP;
#pragma unroll
  for (int j = 0; j < 16; ++j) {
    int dd = ty * 16 + j;
    int t = t0 + tx;
    if (t < NT) vt[base + (size_t)dd * NTP + t] = tile[tx][dd];
  }
}

// ---- flash attention: QBLK=64 (4 waves x 16 rows), KBLK=64, HD=64 ----
// Swapped QK^T (S^T = mfma(K,Q)): lane owns q-row (lane&15), 16 in-lane t.
// In-register softmax (2 shfl max + 2 shfl sum), packed b64 P-writes,
// next-tile K/V register prefetch under compute.
__global__ LB256 void k_attn(const u16* __restrict__ q, const u16* __restrict__ kk,
                             const u16* __restrict__ vt, u16* __restrict__ ox,
                             u16* __restrict__ oc) {
  __shared__ __align__(16) u16 Ks[64][72];
  __shared__ __align__(16) u16 Vs[64][72];
  __shared__ __align__(16) u16 Ps[4][16][72];

  const int lane = threadIdx.x & 63, wid = threadIdx.x >> 6;
  const int g = lane >> 4, r = lane & 15;
  const int q0 = blockIdx.x * 64;
  const int h = blockIdx.y, b = blockIdx.z;
  const size_t bh = (size_t)b * HH + h;
  const u16* qp = q + bh * (NT * 64);
  const u16* kp = kk + bh * (NT * 64);
  const u16* vp = vt + bh * (64 * NTP);

  // Q rows, scale 1/8 folded in at load
  const int qrow = imin(q0 + wid * 16 + r, NT - 1);
  u16x8 qr0 = *(const u16x8*)(qp + (size_t)qrow * 64 + g * 8);
  u16x8 qr1 = *(const u16x8*)(qp + (size_t)qrow * 64 + 32 + g * 8);
  bf16x8 qa0, qa1;
#pragma unroll
  for (int e = 0; e < 8; ++e) {
    qa0[e] = (short)f2bf(bf2f(qr0[e]) * 0.125f);
    qa1[e] = (short)f2bf(bf2f(qr1[e]) * 0.125f);
  }

  f32x4 oacc[4];
#pragma unroll
  for (int i = 0; i < 4; ++i) oacc[i] = fzero4();
  float mrow = -1e30f, lrow = 0.f;

  // staging lanes: thread covers chunks p=0,1 of the 64x64 tile
  int trA[2], ccA[2];
#pragma unroll
  for (int p = 0; p < 2; ++p) {
    int chunk = p * 256 + threadIdx.x;
    trA[p] = chunk >> 3;
    ccA[p] = (chunk & 7) * 8;
  }

  u16x8 kreg[2], vreg[2];
#define LOADKV(T0)                                                         \
  do {                                                                     \
    _Pragma("unroll")                                                      \
    for (int p = 0; p < 2; ++p) {                                          \
      int tsrc = imin((T0) + trA[p], NT - 1);                              \
      kreg[p] = *(const u16x8*)(kp + (size_t)tsrc * 64 + ccA[p]);          \
      int tcol = (T0) + ccA[p];                                            \
      if (tcol + 8 <= NT) {                                                \
        vreg[p] = *(const u16x8*)(vp + (size_t)trA[p] * NTP + tcol);       \
      } else {                                                             \
        _Pragma("unroll")                                                  \
        for (int e = 0; e < 8; ++e)                                        \
          vreg[p][e] = vp[(size_t)trA[p] * NTP + imin(tcol + e, NT - 1)];  \
      }                                                                    \
    }                                                                      \
  } while (0)

  LOADKV(0);

  for (int t0 = 0; t0 < NT; t0 += 64) {
    if (t0) __syncthreads();            // prior tile's LDS reads retired
#pragma unroll
    for (int p = 0; p < 2; ++p) {
      *(u16x8*)&Ks[trA[p]][ccA[p]] = kreg[p];
      *(u16x8*)&Vs[trA[p]][ccA[p]] = vreg[p];
    }
    __syncthreads();                    // tile published
    if (t0 + 64 < NT) LOADKV(t0 + 64);  // prefetch next tile; latency hides under compute

    // S^T = K Q^T (swapped operands; same fragment reads as before)
    f32x4 s[4];
#pragma unroll
    for (int ni = 0; ni < 4; ++ni) {
      s[ni] = fzero4();
      s[ni] = __builtin_amdgcn_mfma_f32_16x16x32_bf16(*(const bf16x8*)&Ks[ni * 16 + r][g * 8], qa0, s[ni], 0, 0, 0);
      s[ni] = __builtin_amdgcn_mfma_f32_16x16x32_bf16(*(const bf16x8*)&Ks[ni * 16 + r][32 + g * 8], qa1, s[ni], 0, 0, 0);
    }

    // lane (g,r) holds S[t = t0 + ni*16 + g*4 + j][q = q-row r]
    float pv[4][4];
    float pm = -1e30f;
#pragma unroll
    for (int ni = 0; ni < 4; ++ni)
#pragma unroll
      for (int j = 0; j < 4; ++j) {
        int t = t0 + ni * 16 + g * 4 + j;
        float sv = (t < NT) ? s[ni][j] : -1e30f;
        pv[ni][j] = sv;
        pm = fmaxf(pm, sv);
      }
    pm = fmaxf(pm, __shfl_xor(pm, 16));
    pm = fmaxf(pm, __shfl_xor(pm, 32));

    float mn = fmaxf(mrow, pm);
    float alpha = __expf(mrow - mn);
    mrow = mn;
    float rs = 0.f;
#pragma unroll
    for (int ni = 0; ni < 4; ++ni)
#pragma unroll
      for (int j = 0; j < 4; ++j) {
        float p = __expf(pv[ni][j] - mn);
        pv[ni][j] = p;
        rs += p;
      }
    rs += __shfl_xor(rs, 16);
    rs += __shfl_xor(rs, 32);
    lrow = lrow * alpha + rs;

    // rescale O: alpha for q = g*4+j lives at lane (g*4+j) (its r == q, g'=0 copy)
#pragma unroll
    for (int j = 0; j < 4; ++j) {
      float aj = __shfl(alpha, g * 4 + j);
#pragma unroll
      for (int ni = 0; ni < 4; ++ni) oacc[ni][j] *= aj;
    }

    // pack P -> bf16 pairs, one b64 write per ni (row = own q-row r)
#pragma unroll
    for (int ni = 0; ni < 4; ++ni) {
      u32x2 w;
      w[0] = (u32)f2bf(pv[ni][0]) | ((u32)f2bf(pv[ni][1]) << 16);
      w[1] = (u32)f2bf(pv[ni][2]) | ((u32)f2bf(pv[ni][3]) << 16);
      *(u32x2*)&Ps[wid][r][ni * 16 + g * 4] = w;
    }

    bf16x8 pa0 = *(const bf16x8*)&Ps[wid][r][g * 8];
    bf16x8 pa1 = *(const bf16x8*)&Ps[wid][r][32 + g * 8];
#pragma unroll
    for (int ni = 0; ni < 4; ++ni) {
      oacc[ni] = __builtin_amdgcn_mfma_f32_16x16x32_bf16(pa0, *(const bf16x8*)&Vs[ni * 16 + r][g * 8], oacc[ni], 0, 0, 0);
      oacc[ni] = __builtin_amdgcn_mfma_f32_16x16x32_bf16(pa1, *(const bf16x8*)&Vs[ni * 16 + r][32 + g * 8], oacc[ni], 0, 0, 0);
    }
  }
#undef LOADKV

  // final 1/l for q = g*4+j
  float linv[4];
#pragma unroll
  for (int j = 0; j < 4; ++j) linv[j] = 1.f / __shfl(lrow, g * 4 + j);

#pragma unroll
  for (int ni = 0; ni < 4; ++ni)
#pragma unroll
    for (int j = 0; j < 4; ++j) {
      int tq = q0 + wid * 16 + g * 4 + j;
      if (tq >= NT) continue;
      float val = oacc[ni][j] * linv[j];
      int col = h * 64 + ni * 16 + r;
      if (tq < NX)
        ox[(size_t)(b * NX + tq) * DD + col] = f2bf(val);
      else
        oc[(size_t)(b * NC + tq - NX) * DD + col] = f2bf(val);
    }
}

extern "C" void kernel_launch(void* const* d_in, const int* in_sizes, int n_in,
                              void* d_out, int out_size, void* d_ws, size_t ws_size,
                              hipStream_t stream) {
  const float* x = (const float*)d_in[0];
  const float* c = (const float*)d_in[1];
  const float* vec = (const float*)d_in[2];
  const float* w_mod = (const float*)d_in[3];
  const float* b_mod = (const float*)d_in[4];
  const float* w_qkv_x = (const float*)d_in[5];
  const float* b_qkv_x = (const float*)d_in[6];
  const float* w_qkv_c = (const float*)d_in[7];
  const float* b_qkv_c = (const float*)d_in[8];
  const float* w_proj_x = (const float*)d_in[9];
  const float* b_proj_x = (const float*)d_in[10];
  const float* w_proj_c = (const float*)d_in[11];
  const float* b_proj_c = (const float*)d_in[12];
  const float* w1_x = (const float*)d_in[13];
  const float* b1_x = (const float*)d_in[14];
  const float* w2_x = (const float*)d_in[15];
  const float* b2_x = (const float*)d_in[16];
  const float* w1_c = (const float*)d_in[17];
  const float* b1_c = (const float*)d_in[18];
  const float* w2_c = (const float*)d_in[19];
  const float* b2_c = (const float*)d_in[20];

  if (ws_size < 229195776ull) return;  // workspace layout below needs this much

  char* ws = (char*)d_ws;
  // persistent: bf16-transposed weights + mod
  u16* wt_qkv_x = (u16*)(ws + 0);
  u16* wt_qkv_c = (u16*)(ws + 14155776);
  u16* wt_proj_x = (u16*)(ws + 28311552);
  u16* wt_proj_c = (u16*)(ws + 33030144);
  u16* wt_w1_x = (u16*)(ws + 37748736);
  u16* wt_w1_c = (u16*)(ws + 56623104);
  u16* wt_w2_x = (u16*)(ws + 75497472);
  u16* wt_w2_c = (u16*)(ws + 94371840);
  float* modf = (float*)(ws + 113246208);
  char* S = ws + 113393664;
  // slot 1 (14,475,264 B): x_n/c_n -> o_x/o_c -> xln/cln -> pb0 (mlp2 partial z=0)
  u16* xn = (u16*)(S);
  u16* cn = (u16*)(S + 12582912);
  // slot 2 (43,425,792 B): qkv_x_out/qkv_c_out -> x2/c2 (f32)
  u16* qkvx = (u16*)(S + 14475264);
  u16* qkvc = (u16*)(S + 52224000);
  float* x2 = (float*)(S + 14475264);   // 25,165,824 B, ends S+39,641,088
  float* c2 = (float*)(S + 39641088);   //  3,784,704 B, ends S+43,425,792
  u16* pb0 = (u16*)(S);                 // 12,582,912 B (xn/cn dead after mlp1 reads)
  u16* pb1 = (u16*)(S + 43425792);      // 12,582,912 B (qkv outputs dead, after c2)
  // partial stride pb0 -> pb1 in u16 elements:
  const int PSTRIDE = 43425792 / 2;     // 21,712,896
  // slot 3 (57,901,056 B): q/k/vt -> h_x/h_c ; head also used as k_mod partials
  u16* qb = (u16*)(S + 57901056);
  u16* kb = (u16*)(S + 72376320);
  u16* vtb = (u16*)(S + 86851584);
  u16* hx = (u16*)(S + 57901056);
  u16* hc = (u16*)(S + 108232704);
  float* modpart = (float*)(S + 57901056);  // 884736 B, dead before q/k/vt written

  // 1) weights -> bf16 transposed
  k_transpose<<<dim3(NQKV / 32, DD / 32), 256, 0, stream>>>(w_qkv_x, wt_qkv_x, DD, NQKV);
  k_transpose<<<dim3(NQKV / 32, DD / 32), 256, 0, stream>>>(w_qkv_c, wt_qkv_c, DD, NQKV);
  k_transpose<<<dim3(DD / 32, DD / 32), 256, 0, stream>>>(w_proj_x, wt_proj_x, DD, DD);
  k_transpose<<<dim3(DD / 32, DD / 32), 256, 0, stream>>>(w_proj_c, wt_proj_c, DD, DD);
  k_transpose<<<dim3(MHD / 32, DD / 32), 256, 0, stream>>>(w1_x, wt_w1_x, DD, MHD);
  k_transpose<<<dim3(MHD / 32, DD / 32), 256, 0, stream>>>(w1_c, wt_w1_c, DD, MHD);
  k_transpose<<<dim3(DD / 32, MHD / 32), 256, 0, stream>>>(w2_x, wt_w2_x, MHD, DD);
  k_transpose<<<dim3(DD / 32, MHD / 32), 256, 0, stream>>>(w2_c, wt_w2_c, MHD, DD);

  // 2) modulation vector (split-K, deterministic two-stage)
  k_mod_part<<<dim3(NMOD / 256, KSPL), 256, 0, stream>>>(vec, w_mod, modpart);
  k_mod_red<<<dim3(NMOD / 256), 256, 0, stream>>>(modpart, b_mod, modf);

  // 3) modulated LN -> bf16
  k_ln<<<dim3(BB * NX), 256, 0, stream>>>(x, xn, modf, 0, DD, NX);
  k_ln<<<dim3(BB * NC), 256, 0, stream>>>(c, cn, modf, 3 * DD, 4 * DD, NC);

  // 4) QKV GEMMs
  k_gemm<0><<<dim3(NQKV / 128, 32), 256, 0, stream>>>(xn, wt_qkv_x, b_qkv_x, BB * NX, NQKV, DD, DD, DD, 0, qkvx, nullptr, nullptr, 0, 1);
  k_gemm<0><<<dim3(NQKV / 128, 5), 256, 0, stream>>>(cn, wt_qkv_c, b_qkv_c, BB * NC, NQKV, DD, DD, DD, 0, qkvc, nullptr, nullptr, 0, 1);

  // 5) reshape to q/k (b,h,t,d) and vt (b,h,d,t)
  k_qk<<<dim3((NT * 64 + 255) / 256, HH, BB), 256, 0, stream>>>(qkvx, qkvc, qb, kb);
  k_vt<<<dim3((NT + 63) / 64, HH, BB), 256, 0, stream>>>(qkvx, qkvc, vtb);

  // 6) flash attention -> o (written into slot 1)
  k_attn<<<dim3((NT + 63) / 64, HH, BB), 256, 0, stream>>>(qb, kb, vtb, xn, cn);

  // 7) output projections with gated residual -> x2/c2 f32
  k_gemm<2><<<dim3(DD / 128, 32), 256, 0, stream>>>(xn, wt_proj_x, b_proj_x, BB * NX, DD, DD, DD, DD, 0, x2, x, modf, 2 * DD, NX);
  k_gemm<2><<<dim3(DD / 128, 5), 256, 0, stream>>>(cn, wt_proj_c, b_proj_c, BB * NC, DD, DD, DD, DD, 0, c2, c, modf, 5 * DD, NC);

  // 8) plain LN -> bf16
  k_ln<<<dim3(BB * NX), 256, 0, stream>>>(x2, xn, nullptr, 0, 0, NX);
  k_ln<<<dim3(BB * NC), 256, 0, stream>>>(c2, cn, nullptr, 0, 0, NC);

  // 9) MLP
  k_gemm<1><<<dim3(MHD / 128, 32), 256, 0, stream>>>(xn, wt_w1_x, b1_x, BB * NX, MHD, DD, DD, DD, 0, hx, nullptr, nullptr, 0, 1);
  k_gemm<1><<<dim3(MHD / 128, 5), 256, 0, stream>>>(cn, wt_w1_c, b1_c, BB * NC, MHD, DD, DD, DD, 0, hc, nullptr, nullptr, 0, 1);

  float* outx = (float*)d_out;
  float* outc = outx + (size_t)BB * NX * DD;
  // mlp2_x: concurrent split-K (z=0: K[0,3072), z=1: K[3072,6144)) -> bf16
  // partials at pb0 / pb0 + PSTRIDE (== pb1, disjoint from live x2/c2) -> reduce
  k_gemm<4><<<dim3(DD / 128, 32, 2), 256, 0, stream>>>(hx, wt_w2_x, b2_x, BB * NX, DD, MHD, MHD, MHD / 2, MHD / 2, pb0, nullptr, nullptr, PSTRIDE, NX);
  k_red<<<dim3(BB * NX), 256, 0, stream>>>(pb0, pb1, x2, b2_x, outx);
  k_gemm<3><<<dim3(DD / 128, 5), 256, 0, stream>>>(hc, wt_w2_c, b2_c, BB * NC, DD, MHD, MHD, MHD, 0, outc, c2, nullptr, 0, NC);
}

// Round 7
// 862.283 us; speedup vs baseline: 1.3210x; 1.0019x over previous
//
#include <hip/hip_runtime.h>
#include <stdint.h>

typedef unsigned short u16;
typedef unsigned int u32;
typedef __attribute__((ext_vector_type(8))) short bf16x8;
typedef __attribute__((ext_vector_type(8))) unsigned short u16x8;
typedef __attribute__((ext_vector_type(2))) unsigned int u32x2;
typedef __attribute__((ext_vector_type(4))) float f32x4;

#define LB256 __launch_bounds__(256, 2)

// ---- problem dims ----
#define BB 4
#define NX 1024
#define NC 154
#define NT 1178
#define NTP 1184   // padded t stride for V^T (16B-aligned rows)
#define DD 1536
#define HH 24
#define MHD 6144
#define NQKV 4608
#define NMOD 9216
#define KSPL 6

__device__ __forceinline__ int imin(int a, int b) { return a < b ? a : b; }

__device__ __forceinline__ u16 f2bf(float f) {
  u32 u = __float_as_uint(f);
  u32 r = (u + 0x7fffu + ((u >> 16) & 1u)) >> 16;
  return (u16)r;
}

__device__ __forceinline__ float bf2f(u16 v) {
  u32 u = ((u32)v) << 16;
  return __uint_as_float(u);
}

__device__ __forceinline__ float gelu_t(float x) {
  float x2 = x * x;
  float t = tanhf(0.7978845608028654f * x * (1.f + 0.044715f * x2));
  return 0.5f * x * (1.f + t);
}

__device__ __forceinline__ f32x4 fzero4() {
  f32x4 z; z[0] = 0.f; z[1] = 0.f; z[2] = 0.f; z[3] = 0.f; return z;
}

// async global->LDS, 16B per lane; LDS dest = wave-uniform base + lane*16
__device__ __forceinline__ void glds16(const u16* g, u16* l) {
  __builtin_amdgcn_global_load_lds(
      (const __attribute__((address_space(1))) void*)g,
      (__attribute__((address_space(3))) void*)l, 16, 0, 0);
}

#define WAITV4 asm volatile("s_waitcnt vmcnt(4)" ::: "memory")
#define WAITV0 asm volatile("s_waitcnt vmcnt(0)" ::: "memory")
#define SCHEDB __builtin_amdgcn_sched_barrier(0)

// ---- weight transpose + f32->bf16: W[K][N] -> Wt[N][K] ----
__global__ void k_transpose(const float* __restrict__ W, u16* __restrict__ Wt, int K, int N) {
  __shared__ float tile[32][33];
  int n0 = blockIdx.x * 32, k0 = blockIdx.y * 32;
  int tx = threadIdx.x & 31, ty = threadIdx.x >> 5;  // 32 x 8
#pragma unroll
  for (int j = 0; j < 32; j += 8)
    tile[ty + j][tx] = W[(size_t)(k0 + ty + j) * N + n0 + tx];
  __syncthreads();
#pragma unroll
  for (int j = 0; j < 32; j += 8)
    Wt[(size_t)(n0 + ty + j) * K + k0 + tx] = f2bf(tile[tx][ty + j]);
}

// ---- mod = silu(vec) @ w_mod + b_mod : split-K partials (deterministic) ----
__global__ void k_mod_part(const float* __restrict__ vec, const float* __restrict__ w_mod,
                           float* __restrict__ part) {
  __shared__ float sv[BB][256];
  int n = blockIdx.x * 256 + threadIdx.x;
  int kb = blockIdx.y;
  int k0 = kb * 256;
  for (int i = threadIdx.x; i < BB * 256; i += 256) {
    int b = i >> 8, kk = i & 255;
    float v = vec[b * DD + k0 + kk];
    sv[b][kk] = v / (1.f + __expf(-v));
  }
  __syncthreads();
  float a0 = 0.f, a1 = 0.f, a2 = 0.f, a3 = 0.f;
  for (int k = 0; k < 256; ++k) {
    float w = w_mod[(size_t)(k0 + k) * NMOD + n];
    a0 = fmaf(sv[0][k], w, a0);
    a1 = fmaf(sv[1][k], w, a1);
    a2 = fmaf(sv[2][k], w, a2);
    a3 = fmaf(sv[3][k], w, a3);
  }
  part[((size_t)kb * BB + 0) * NMOD + n] = a0;
  part[((size_t)kb * BB + 1) * NMOD + n] = a1;
  part[((size_t)kb * BB + 2) * NMOD + n] = a2;
  part[((size_t)kb * BB + 3) * NMOD + n] = a3;
}

__global__ void k_mod_red(const float* __restrict__ part, const float* __restrict__ b_mod,
                          float* __restrict__ mod) {
  int n = blockIdx.x * 256 + threadIdx.x;
  float bb = b_mod[n];
#pragma unroll
  for (int b = 0; b < BB; ++b) {
    float s = bb;
#pragma unroll
    for (int kb = 0; kb < KSPL; ++kb) s += part[((size_t)kb * BB + b) * NMOD + n];
    mod[b * NMOD + n] = s;
  }
}

// ---- LayerNorm (optionally modulated) f32 -> bf16 ----
__global__ LB256 void k_ln(const float* __restrict__ in, u16* __restrict__ out,
                           const float* __restrict__ modp, int sh_off, int sc_off,
                           int rows_per_b) {
  int row = blockIdx.x;
  int b = row / rows_per_b;
  const float* xr = in + (size_t)row * DD;
  float v[6];
  float s = 0.f, s2 = 0.f;
#pragma unroll
  for (int i = 0; i < 6; ++i) {
    float t = xr[threadIdx.x + 256 * i];
    v[i] = t; s += t; s2 += t * t;
  }
#pragma unroll
  for (int m = 32; m >= 1; m >>= 1) {
    s += __shfl_xor(s, m);
    s2 += __shfl_xor(s2, m);
  }
  __shared__ float red[8];
  int wid = threadIdx.x >> 6;
  if ((threadIdx.x & 63) == 0) { red[wid] = s; red[4 + wid] = s2; }
  __syncthreads();
  s = red[0] + red[1] + red[2] + red[3];
  s2 = red[4] + red[5] + red[6] + red[7];
  float mean = s * (1.f / (float)DD);
  float var = s2 * (1.f / (float)DD) - mean * mean;
  float rstd = rsqrtf(var + 1e-6f);
#pragma unroll
  for (int i = 0; i < 6; ++i) {
    int d = threadIdx.x + 256 * i;
    float y = (v[i] - mean) * rstd;
    if (modp) y = y * (1.f + modp[b * NMOD + sc_off + d]) + modp[b * NMOD + sh_off + d];
    out[(size_t)row * DD + d] = f2bf(y);
  }
}

// ---- 256x256x64 8-wave deep-pipelined GEMM (m198/m201-style, plain HIP) ----
// Requires M%256==0, N%256==0, K%64==0. C = A(MxK) @ Bt(NxK)^T + bias.
// 2x64KB LDS K-tile double-buffer; full next-tile staging issued at tile start
// (16 gload_lds covered by ~4 MFMA phases); XOR swizzle slot^=(row&7) applied
// on BOTH sides (pre-swizzled global src + swizzled ds_read). One barrier/tile.
// EPI: 0 bias->bf16 | 1 gelu(bias+acc)->bf16
template <int EPI>
__global__ __launch_bounds__(512, 2) void k_gemm256(
    const u16* __restrict__ A, const u16* __restrict__ Bt,
    const float* __restrict__ bias, int N, int lda, int ldb, int kLen,
    u16* __restrict__ outp) {
  __shared__ __align__(16) u16 sm[2][32768];  // [buf][A 16K u16 | B 16K u16]
  const int tid = threadIdx.x;
  const int lane = tid & 63;
  const int g = lane >> 4, r = lane & 15;
  const int wid = tid >> 6;
  const int wr = wid >> 2, wc = wid & 3;  // 2M x 4N wave grid

  // bijective XCD-aware tile remap (m204)
  const int gx = gridDim.x;
  const int nwg = gx * gridDim.y;
  int wg = blockIdx.y * gx + blockIdx.x;
  {
    int q = nwg >> 3, rr = nwg & 7;
    int xcd = wg & 7, sl = wg >> 3;
    wg = (xcd < rr ? xcd * (q + 1) : rr * (q + 1) + (xcd - rr) * q) + sl;
  }
  const int m0 = (wg / gx) * 256, n0 = (wg % gx) * 256;

  f32x4 acc[8][4];
#pragma unroll
  for (int i = 0; i < 8; ++i)
#pragma unroll
    for (int j = 0; j < 4; ++j) acc[i][j] = fzero4();

  // staging: waves 0-3 stage A (2048 16B units), waves 4-7 stage B.
  // instr i of wave: unit u = (wid&3)*512 + i*64 + lane ; row = u>>3, ps = u&7.
  // phys slot ps holds logical slot ls = ps ^ (row&7); here ps = lane&7,
  // row&7 = (lane>>3)&7 (both constant across i).
  const bool isB = wid >= 4;
  const int u_base = (wid & 3) * 512;
  const int ls = (lane & 7) ^ ((lane >> 3) & 7);
  const int row0 = (u_base >> 3) + (lane >> 3);  // + i*8 per instr
  const u16* src = isB ? Bt : A;
  const int ld = isB ? ldb : lda;
  const int b0 = isB ? n0 : m0;
  const size_t g0 = (size_t)(b0 + row0) * ld + ls * 8;
  const int ldsb = (isB ? 16384 : 0) + u_base * 8;  // u16 idx, + i*512

#define STAGE256(BI, T)                                                  \
  do {                                                                   \
    _Pragma("unroll") for (int i = 0; i < 8; ++i)                        \
        glds16(src + g0 + (size_t)i * 8 * ld + (size_t)(T) * 64,         \
               &sm[BI][ldsb + i * 512]);                                 \
  } while (0)

  const int nt = kLen >> 6;  // K-tiles of 64
  STAGE256(0, 0);

  const int swz0 = (g ^ (r & 7)) * 8;        // ksub 0: logical slot g
  const int swz1 = ((4 + g) ^ (r & 7)) * 8;  // ksub 1: logical slot 4+g

  for (int t = 0; t < nt; ++t) {
    WAITV0;                        // my 8 staging loads for tile t landed
    __builtin_amdgcn_s_barrier();  // all waves' tile-t data published
    SCHEDB;                        // nothing crosses the barrier
    if (t + 1 < nt) STAGE256((t + 1) & 1, t + 1);  // lands during 4 phases
    const u16* sA = &sm[t & 1][0];
    const u16* sB = &sm[t & 1][16384];
#pragma unroll
    for (int mh = 0; mh < 2; ++mh) {
#pragma unroll
      for (int nh = 0; nh < 2; ++nh) {
        bf16x8 af[4][2], bfv[2][2];
#pragma unroll
        for (int mi = 0; mi < 4; ++mi) {
          const int ar = wr * 128 + mh * 64 + mi * 16 + r;  // ar&7 == r&7
          af[mi][0] = *(const bf16x8*)&sA[ar * 64 + swz0];
          af[mi][1] = *(const bf16x8*)&sA[ar * 64 + swz1];
        }
#pragma unroll
        for (int ni = 0; ni < 2; ++ni) {
          const int br = wc * 64 + nh * 32 + ni * 16 + r;
          bfv[ni][0] = *(const bf16x8*)&sB[br * 64 + swz0];
          bfv[ni][1] = *(const bf16x8*)&sB[br * 64 + swz1];
        }
        __builtin_amdgcn_s_setprio(1);
#pragma unroll
        for (int mi = 0; mi < 4; ++mi)
#pragma unroll
          for (int ni = 0; ni < 2; ++ni) {
            acc[mh * 4 + mi][nh * 2 + ni] = __builtin_amdgcn_mfma_f32_16x16x32_bf16(
                af[mi][0], bfv[ni][0], acc[mh * 4 + mi][nh * 2 + ni], 0, 0, 0);
            acc[mh * 4 + mi][nh * 2 + ni] = __builtin_amdgcn_mfma_f32_16x16x32_bf16(
                af[mi][1], bfv[ni][1], acc[mh * 4 + mi][nh * 2 + ni], 0, 0, 0);
          }
        __builtin_amdgcn_s_setprio(0);
      }
    }
    SCHEDB;  // keep the tile body ahead of next iteration's WAITV0
  }
#undef STAGE256

#pragma unroll
  for (int mi = 0; mi < 8; ++mi) {
#pragma unroll
    for (int ni = 0; ni < 4; ++ni) {
      const int col = n0 + wc * 64 + ni * 16 + r;
      const float bv = bias[col];
#pragma unroll
      for (int j = 0; j < 4; ++j) {
        const int row = m0 + wr * 128 + mi * 16 + g * 4 + j;
        const size_t off = (size_t)row * N + col;
        if constexpr (EPI == 0)
          outp[off] = f2bf(acc[mi][ni][j] + bv);
        else
          outp[off] = f2bf(gelu_t(acc[mi][ni][j] + bv));
      }
    }
  }
}

// ---- pipelined bf16 MFMA GEMM: C = A(MxK) @ Bt(NxK)^T (+bias), 128x128x32 tile
// 3-buffer LDS, counted vmcnt(4), single raw barrier per K-step, XOR-swizzled LDS.
// EPI: 0 bias->bf16 | 1 gelu(bias+acc)->bf16 | 2 resid+g*(acc+bias)->f32 |
//      3 resid+acc+bias->f32 | 4 acc->bf16 partial at outp + z*goff (split-K)
template <int EPI>
__global__ LB256 void k_gemm(const u16* __restrict__ A, const u16* __restrict__ Bt,
                             const float* __restrict__ bias, int M, int N,
                             int lda, int ldb, int kLen, int kzOff,
                             void* __restrict__ outp, const float* __restrict__ resid,
                             const float* __restrict__ modp, int goff, int rows_per_b) {
  __shared__ __align__(16) u16 sm[3 * 8192];  // 3 x (A 4096 + B 4096) u16 = 48 KB
  const int tid = threadIdx.x;
  const int lane = tid & 63;
  const int g = lane >> 4, r = lane & 15;
  const int wid = tid >> 6;

  // bijective XCD-aware tile remap (m204)
  const int gx = gridDim.x;
  const int nwg = gx * gridDim.y;
  int wg = blockIdx.y * gx + blockIdx.x;
  {
    int q = nwg >> 3, rr = nwg & 7;
    int xcd = wg & 7, sl = wg >> 3;
    wg = (xcd < rr ? xcd * (q + 1) : rr * (q + 1) + (xcd - rr) * q) + sl;
  }
  const int m0 = (wg / gx) * 128, n0 = (wg % gx) * 128;
  const int wm = (wid >> 1) * 64, wn = (wid & 1) * 64;

  A += (size_t)blockIdx.z * kzOff;
  Bt += (size_t)blockIdx.z * kzOff;

  f32x4 acc[4][4];
#pragma unroll
  for (int i = 0; i < 4; ++i)
#pragma unroll
    for (int j = 0; j < 4; ++j) acc[i][j] = fzero4();

  // staging geometry: tile (A or B) = 8 chunks of 1KB; wave wid owns chunks
  // c0=wid*2, c1=wid*2+1. lane l -> phys row c*16 + l/4, phys slot l&3.
  // phys slot s holds logical slot s ^ ((row>>1)&3); (row>>1)&3 == (l>>3)&3.
  const int rl = lane >> 2;
  const int slg = (lane & 3) ^ ((lane >> 3) & 3);
  const int c0 = wid * 2, c1 = wid * 2 + 1;
  const size_t aR0 = (size_t)imin(m0 + c0 * 16 + rl, M - 1) * lda + slg * 8;
  const size_t aR1 = (size_t)imin(m0 + c1 * 16 + rl, M - 1) * lda + slg * 8;
  const size_t bR0 = (size_t)(n0 + c0 * 16 + rl) * ldb + slg * 8;
  const size_t bR1 = (size_t)(n0 + c1 * 16 + rl) * ldb + slg * 8;

  // read-side swizzled u16 offsets: fragment row = wm+mi*16+r -> (row>>1)&3 == (r>>1)&3
  int aOff[4], bOff[4];
#pragma unroll
  for (int mi = 0; mi < 4; ++mi) aOff[mi] = (wm + mi * 16 + r) * 32 + ((g ^ ((r >> 1) & 3)) * 8);
#pragma unroll
  for (int ni = 0; ni < 4; ++ni) bOff[ni] = 4096 + (wn + ni * 16 + r) * 32 + ((g ^ ((r >> 1) & 3)) * 8);

  const int nt = kLen >> 5;  // K-steps of 32

#define STAGE(BI, T)                                        \
  do {                                                      \
    u16* bb = &sm[(BI) * 8192];                             \
    size_t kk = (size_t)(T) * 32;                           \
    glds16(A + aR0 + kk, bb + c0 * 512);                    \
    glds16(A + aR1 + kk, bb + c1 * 512);                    \
    glds16(Bt + bR0 + kk, bb + 4096 + c0 * 512);            \
    glds16(Bt + bR1 + kk, bb + 4096 + c1 * 512);            \
  } while (0)

  // prologue: tiles 0,1 -> bufs 0,1  (8 loads in flight per wave)
  STAGE(0, 0);
  STAGE(1, 1);

  for (int t = 0; t < nt - 1; ++t) {
    WAITV4;                              // my tile-t loads landed (t+1 in flight)
    __builtin_amdgcn_s_barrier();        // all waves' tile-t data published
    SCHEDB;                              // pin STAGE/ds_reads below the barrier
    if (t + 2 < nt) STAGE((t + 2) % 3, t + 2);  // overwrites tile t-1's buf (reads retired)
    const u16* bb = &sm[(t % 3) * 8192];
    bf16x8 af[4], bfr[4];
#pragma unroll
    for (int mi = 0; mi < 4; ++mi) af[mi] = *(const bf16x8*)(bb + aOff[mi]);
#pragma unroll
    for (int ni = 0; ni < 4; ++ni) bfr[ni] = *(const bf16x8*)(bb + bOff[ni]);
    __builtin_amdgcn_s_setprio(1);
#pragma unroll
    for (int mi = 0; mi < 4; ++mi)
#pragma unroll
      for (int ni = 0; ni < 4; ++ni)
        acc[mi][ni] = __builtin_amdgcn_mfma_f32_16x16x32_bf16(af[mi], bfr[ni], acc[mi][ni], 0, 0, 0);
    __builtin_amdgcn_s_setprio(0);
    SCHEDB;                              // pin this iteration's body before next WAITV
  }
  // tail iteration
  {
    WAITV0;
    __builtin_amdgcn_s_barrier();
    SCHEDB;
    const u16* bb = &sm[((nt - 1) % 3) * 8192];
    bf16x8 af[4], bfr[4];
#pragma unroll
    for (int mi = 0; mi < 4; ++mi) af[mi] = *(const bf16x8*)(bb + aOff[mi]);
#pragma unroll
    for (int ni = 0; ni < 4; ++ni) bfr[ni] = *(const bf16x8*)(bb + bOff[ni]);
#pragma unroll
    for (int mi = 0; mi < 4; ++mi)
#pragma unroll
      for (int ni = 0; ni < 4; ++ni)
        acc[mi][ni] = __builtin_amdgcn_mfma_f32_16x16x32_bf16(af[mi], bfr[ni], acc[mi][ni], 0, 0, 0);
  }
#undef STAGE

#pragma unroll
  for (int mi = 0; mi < 4; ++mi) {
#pragma unroll
    for (int ni = 0; ni < 4; ++ni) {
      const int col = n0 + wn + ni * 16 + r;
      float bv = 0.f;
      if constexpr (EPI != 4) bv = bias[col];
#pragma unroll
      for (int j = 0; j < 4; ++j) {
        const int row = m0 + wm + mi * 16 + g * 4 + j;
        if (row >= M) continue;
        const size_t off = (size_t)row * N + col;
        if constexpr (EPI == 0) {
          ((u16*)outp)[off] = f2bf(acc[mi][ni][j] + bv);
        } else if constexpr (EPI == 1) {
          ((u16*)outp)[off] = f2bf(gelu_t(acc[mi][ni][j] + bv));
        } else if constexpr (EPI == 2) {
          const int b = row / rows_per_b;
          ((float*)outp)[off] = resid[off] + modp[b * NMOD + goff + col] * (acc[mi][ni][j] + bv);
        } else if constexpr (EPI == 3) {
          ((float*)outp)[off] = resid[off] + acc[mi][ni][j] + bv;
        } else {
          ((u16*)outp)[(size_t)blockIdx.z * (size_t)goff + off] = f2bf(acc[mi][ni][j]);
        }
      }
    }
  }
}

// ---- split-K reduce for mlp2_x: out = resid + bias + p0 + p1 ----
__global__ void k_red(const u16* __restrict__ p0, const u16* __restrict__ p1,
                      const float* __restrict__ resid, const float* __restrict__ bias,
                      float* __restrict__ out) {
  size_t base = (size_t)blockIdx.x * DD;
#pragma unroll
  for (int i = 0; i < 6; ++i) {
    int j = threadIdx.x + 256 * i;
    out[base + j] = resid[base + j] + bias[j] + bf2f(p0[base + j]) + bf2f(p1[base + j]);
  }
}

// ---- scatter qkv GEMM output into q,k (b,h,t,d) bf16 ----
__global__ void k_qk(const u16* __restrict__ qkvx, const u16* __restrict__ qkvc,
                     u16* __restrict__ q, u16* __restrict__ k) {
  int idx = blockIdx.x * 256 + threadIdx.x;
  if (idx >= NT * 64) return;
  int t = idx >> 6, d = idx & 63;
  int h = blockIdx.y, b = blockIdx.z;
  const u16* src = (t < NX) ? qkvx + (size_t)(b * NX + t) * NQKV
                            : qkvc + (size_t)(b * NC + t - NX) * NQKV;
  size_t o = ((size_t)(b * HH + h) * NT + t) * 64 + d;
  q[o] = src[h * 64 + d];
  k[o] = src[DD + h * 64 + d];
}

// ---- V transpose: qkv v-cols -> vt (b,h,d,t) bf16, t-stride NTP ----
__global__ void k_vt(const u16* __restrict__ qkvx, const u16* __restrict__ qkvc,
                     u16* __restrict__ vt) {
  __shared__ u16 tile[64][65];
  int t0 = blockIdx.x * 64;
  int h = blockIdx.y, b = blockIdx.z;
  int tx = threadIdx.x & 63, ty = threadIdx.x >> 6;
#pragma unroll
  for (int j = 0; j < 16; ++j) {
    int tt = ty * 16 + j;
    int t = t0 + tt;
    if (t < NT) {
      const u16* src = (t < NX) ? qkvx + (size_t)(b * NX + t) * NQKV
                                : qkvc + (size_t)(b * NC + t - NX) * NQKV;
      tile[tt][tx] = src[2 * DD + h * 64 + tx];
    }
  }
  __syncthreads();
  size_t base = (size_t)(b * HH + h) * 64 * NTP;
#pragma unroll
  for (int j = 0; j < 16; ++j) {
    int dd = ty * 16 + j;
    int t = t0 + tx;
    if (t < NT) vt[base + (size_t)dd * NTP + t] = tile[tx][dd];
  }
}

// ---- flash attention: QBLK=64 (4 waves x 16 rows), KBLK=64, HD=64 ----
// Swapped QK^T (S^T = mfma(K,Q)): lane owns q-row (lane&15), 16 in-lane t.
// In-register softmax (2 shfl max + 2 shfl sum), packed b64 P-writes,
// next-tile K/V register prefetch under compute.
__global__ LB256 void k_attn(const u16* __restrict__ q, const u16* __restrict__ kk,
                             const u16* __restrict__ vt, u16* __restrict__ ox,
                             u16* __restrict__ oc) {
  __shared__ __align__(16) u16 Ks[64][72];
  __shared__ __align__(16) u16 Vs[64][72];
  __shared__ __align__(16) u16 Ps[4][16][72];

  const int lane = threadIdx.x & 63, wid = threadIdx.x >> 6;
  const int g = lane >> 4, r = lane & 15;
  const int q0 = blockIdx.x * 64;
  const int h = blockIdx.y, b = blockIdx.z;
  const size_t bh = (size_t)b * HH + h;
  const u16* qp = q + bh * (NT * 64);
  const u16* kp = kk + bh * (NT * 64);
  const u16* vp = vt + bh * (64 * NTP);

  // Q rows, scale 1/8 folded in at load
  const int qrow = imin(q0 + wid * 16 + r, NT - 1);
  u16x8 qr0 = *(const u16x8*)(qp + (size_t)qrow * 64 + g * 8);
  u16x8 qr1 = *(const u16x8*)(qp + (size_t)qrow * 64 + 32 + g * 8);
  bf16x8 qa0, qa1;
#pragma unroll
  for (int e = 0; e < 8; ++e) {
    qa0[e] = (short)f2bf(bf2f(qr0[e]) * 0.125f);
    qa1[e] = (short)f2bf(bf2f(qr1[e]) * 0.125f);
  }

  f32x4 oacc[4];
#pragma unroll
  for (int i = 0; i < 4; ++i) oacc[i] = fzero4();
  float mrow = -1e30f, lrow = 0.f;

  // staging lanes: thread covers chunks p=0,1 of the 64x64 tile
  int trA[2], ccA[2];
#pragma unroll
  for (int p = 0; p < 2; ++p) {
    int chunk = p * 256 + threadIdx.x;
    trA[p] = chunk >> 3;
    ccA[p] = (chunk & 7) * 8;
  }

  u16x8 kreg[2], vreg[2];
#define LOADKV(T0)                                                         \
  do {                                                                     \
    _Pragma("unroll")                                                      \
    for (int p = 0; p < 2; ++p) {                                          \
      int tsrc = imin((T0) + trA[p], NT - 1);                              \
      kreg[p] = *(const u16x8*)(kp + (size_t)tsrc * 64 + ccA[p]);          \
      int tcol = (T0) + ccA[p];                                            \
      if (tcol + 8 <= NT) {                                                \
        vreg[p] = *(const u16x8*)(vp + (size_t)trA[p] * NTP + tcol);       \
      } else {                                                             \
        _Pragma("unroll")                                                  \
        for (int e = 0; e < 8; ++e)                                        \
          vreg[p][e] = vp[(size_t)trA[p] * NTP + imin(tcol + e, NT - 1)];  \
      }                                                                    \
    }                                                                      \
  } while (0)

  LOADKV(0);

  for (int t0 = 0; t0 < NT; t0 += 64) {
    if (t0) __syncthreads();            // prior tile's LDS reads retired
#pragma unroll
    for (int p = 0; p < 2; ++p) {
      *(u16x8*)&Ks[trA[p]][ccA[p]] = kreg[p];
      *(u16x8*)&Vs[trA[p]][ccA[p]] = vreg[p];
    }
    __syncthreads();                    // tile published
    if (t0 + 64 < NT) LOADKV(t0 + 64);  // prefetch next tile; latency hides under compute

    // S^T = K Q^T (swapped operands; same fragment reads as before)
    f32x4 s[4];
#pragma unroll
    for (int ni = 0; ni < 4; ++ni) {
      s[ni] = fzero4();
      s[ni] = __builtin_amdgcn_mfma_f32_16x16x32_bf16(*(const bf16x8*)&Ks[ni * 16 + r][g * 8], qa0, s[ni], 0, 0, 0);
      s[ni] = __builtin_amdgcn_mfma_f32_16x16x32_bf16(*(const bf16x8*)&Ks[ni * 16 + r][32 + g * 8], qa1, s[ni], 0, 0, 0);
    }

    // lane (g,r) holds S[t = t0 + ni*16 + g*4 + j][q = q-row r]
    float pv[4][4];
    float pm = -1e30f;
#pragma unroll
    for (int ni = 0; ni < 4; ++ni)
#pragma unroll
      for (int j = 0; j < 4; ++j) {
        int t = t0 + ni * 16 + g * 4 + j;
        float sv = (t < NT) ? s[ni][j] : -1e30f;
        pv[ni][j] = sv;
        pm = fmaxf(pm, sv);
      }
    pm = fmaxf(pm, __shfl_xor(pm, 16));
    pm = fmaxf(pm, __shfl_xor(pm, 32));

    float mn = fmaxf(mrow, pm);
    float alpha = __expf(mrow - mn);
    mrow = mn;
    float rs = 0.f;
#pragma unroll
    for (int ni = 0; ni < 4; ++ni)
#pragma unroll
      for (int j = 0; j < 4; ++j) {
        float p = __expf(pv[ni][j] - mn);
        pv[ni][j] = p;
        rs += p;
      }
    rs += __shfl_xor(rs, 16);
    rs += __shfl_xor(rs, 32);
    lrow = lrow * alpha + rs;

    // rescale O: alpha for q = g*4+j lives at lane (g*4+j) (its r == q, g'=0 copy)
#pragma unroll
    for (int j = 0; j < 4; ++j) {
      float aj = __shfl(alpha, g * 4 + j);
#pragma unroll
      for (int ni = 0; ni < 4; ++ni) oacc[ni][j] *= aj;
    }

    // pack P -> bf16 pairs, one b64 write per ni (row = own q-row r)
#pragma unroll
    for (int ni = 0; ni < 4; ++ni) {
      u32x2 w;
      w[0] = (u32)f2bf(pv[ni][0]) | ((u32)f2bf(pv[ni][1]) << 16);
      w[1] = (u32)f2bf(pv[ni][2]) | ((u32)f2bf(pv[ni][3]) << 16);
      *(u32x2*)&Ps[wid][r][ni * 16 + g * 4] = w;
    }

    bf16x8 pa0 = *(const bf16x8*)&Ps[wid][r][g * 8];
    bf16x8 pa1 = *(const bf16x8*)&Ps[wid][r][32 + g * 8];
#pragma unroll
    for (int ni = 0; ni < 4; ++ni) {
      oacc[ni] = __builtin_amdgcn_mfma_f32_16x16x32_bf16(pa0, *(const bf16x8*)&Vs[ni * 16 + r][g * 8], oacc[ni], 0, 0, 0);
      oacc[ni] = __builtin_amdgcn_mfma_f32_16x16x32_bf16(pa1, *(const bf16x8*)&Vs[ni * 16 + r][32 + g * 8], oacc[ni], 0, 0, 0);
    }
  }
#undef LOADKV

  // final 1/l for q = g*4+j
  float linv[4];
#pragma unroll
  for (int j = 0; j < 4; ++j) linv[j] = 1.f / __shfl(lrow, g * 4 + j);

#pragma unroll
  for (int ni = 0; ni < 4; ++ni)
#pragma unroll
    for (int j = 0; j < 4; ++j) {
      int tq = q0 + wid * 16 + g * 4 + j;
      if (tq >= NT) continue;
      float val = oacc[ni][j] * linv[j];
      int col = h * 64 + ni * 16 + r;
      if (tq < NX)
        ox[(size_t)(b * NX + tq) * DD + col] = f2bf(val);
      else
        oc[(size_t)(b * NC + tq - NX) * DD + col] = f2bf(val);
    }
}

extern "C" void kernel_launch(void* const* d_in, const int* in_sizes, int n_in,
                              void* d_out, int out_size, void* d_ws, size_t ws_size,
                              hipStream_t stream) {
  const float* x = (const float*)d_in[0];
  const float* c = (const float*)d_in[1];
  const float* vec = (const float*)d_in[2];
  const float* w_mod = (const float*)d_in[3];
  const float* b_mod = (const float*)d_in[4];
  const float* w_qkv_x = (const float*)d_in[5];
  const float* b_qkv_x = (const float*)d_in[6];
  const float* w_qkv_c = (const float*)d_in[7];
  const float* b_qkv_c = (const float*)d_in[8];
  const float* w_proj_x = (const float*)d_in[9];
  const float* b_proj_x = (const float*)d_in[10];
  const float* w_proj_c = (const float*)d_in[11];
  const float* b_proj_c = (const float*)d_in[12];
  const float* w1_x = (const float*)d_in[13];
  const float* b1_x = (const float*)d_in[14];
  const float* w2_x = (const float*)d_in[15];
  const float* b2_x = (const float*)d_in[16];
  const float* w1_c = (const float*)d_in[17];
  const float* b1_c = (const float*)d_in[18];
  const float* w2_c = (const float*)d_in[19];
  const float* b2_c = (const float*)d_in[20];

  if (ws_size < 229195776ull) return;  // workspace layout below needs this much

  char* ws = (char*)d_ws;
  // persistent: bf16-transposed weights + mod
  u16* wt_qkv_x = (u16*)(ws + 0);
  u16* wt_qkv_c = (u16*)(ws + 14155776);
  u16* wt_proj_x = (u16*)(ws + 28311552);
  u16* wt_proj_c = (u16*)(ws + 33030144);
  u16* wt_w1_x = (u16*)(ws + 37748736);
  u16* wt_w1_c = (u16*)(ws + 56623104);
  u16* wt_w2_x = (u16*)(ws + 75497472);
  u16* wt_w2_c = (u16*)(ws + 94371840);
  float* modf = (float*)(ws + 113246208);
  char* S = ws + 113393664;
  // slot 1 (14,475,264 B): x_n/c_n -> o_x/o_c -> xln/cln -> pb0 (mlp2 partial z=0)
  u16* xn = (u16*)(S);
  u16* cn = (u16*)(S + 12582912);
  // slot 2 (43,425,792 B): qkv_x_out/qkv_c_out -> x2/c2 (f32)
  u16* qkvx = (u16*)(S + 14475264);
  u16* qkvc = (u16*)(S + 52224000);
  float* x2 = (float*)(S + 14475264);   // 25,165,824 B, ends S+39,641,088
  float* c2 = (float*)(S + 39641088);   //  3,784,704 B, ends S+43,425,792
  u16* pb0 = (u16*)(S);                 // 12,582,912 B (xn/cn dead after mlp1 reads)
  u16* pb1 = (u16*)(S + 43425792);      // 12,582,912 B (qkv outputs dead, after c2)
  // partial stride pb0 -> pb1 in u16 elements:
  const int PSTRIDE = 43425792 / 2;     // 21,712,896
  // slot 3 (57,901,056 B): q/k/vt -> h_x/h_c ; head also used as k_mod partials
  u16* qb = (u16*)(S + 57901056);
  u16* kb = (u16*)(S + 72376320);
  u16* vtb = (u16*)(S + 86851584);
  u16* hx = (u16*)(S + 57901056);
  u16* hc = (u16*)(S + 108232704);
  float* modpart = (float*)(S + 57901056);  // 884736 B, dead before q/k/vt written

  // 1) weights -> bf16 transposed
  k_transpose<<<dim3(NQKV / 32, DD / 32), 256, 0, stream>>>(w_qkv_x, wt_qkv_x, DD, NQKV);
  k_transpose<<<dim3(NQKV / 32, DD / 32), 256, 0, stream>>>(w_qkv_c, wt_qkv_c, DD, NQKV);
  k_transpose<<<dim3(DD / 32, DD / 32), 256, 0, stream>>>(w_proj_x, wt_proj_x, DD, DD);
  k_transpose<<<dim3(DD / 32, DD / 32), 256, 0, stream>>>(w_proj_c, wt_proj_c, DD, DD);
  k_transpose<<<dim3(MHD / 32, DD / 32), 256, 0, stream>>>(w1_x, wt_w1_x, DD, MHD);
  k_transpose<<<dim3(MHD / 32, DD / 32), 256, 0, stream>>>(w1_c, wt_w1_c, DD, MHD);
  k_transpose<<<dim3(DD / 32, MHD / 32), 256, 0, stream>>>(w2_x, wt_w2_x, MHD, DD);
  k_transpose<<<dim3(DD / 32, MHD / 32), 256, 0, stream>>>(w2_c, wt_w2_c, MHD, DD);

  // 2) modulation vector (split-K, deterministic two-stage)
  k_mod_part<<<dim3(NMOD / 256, KSPL), 256, 0, stream>>>(vec, w_mod, modpart);
  k_mod_red<<<dim3(NMOD / 256), 256, 0, stream>>>(modpart, b_mod, modf);

  // 3) modulated LN -> bf16
  k_ln<<<dim3(BB * NX), 256, 0, stream>>>(x, xn, modf, 0, DD, NX);
  k_ln<<<dim3(BB * NC), 256, 0, stream>>>(c, cn, modf, 3 * DD, 4 * DD, NC);

  // 4) QKV GEMMs (x-stream on 256x256 8-wave kernel)
  k_gemm256<0><<<dim3(NQKV / 256, (BB * NX) / 256), 512, 0, stream>>>(xn, wt_qkv_x, b_qkv_x, NQKV, DD, DD, DD, qkvx);
  k_gemm<0><<<dim3(NQKV / 128, 5), 256, 0, stream>>>(cn, wt_qkv_c, b_qkv_c, BB * NC, NQKV, DD, DD, DD, 0, qkvc, nullptr, nullptr, 0, 1);

  // 5) reshape to q/k (b,h,t,d) and vt (b,h,d,t)
  k_qk<<<dim3((NT * 64 + 255) / 256, HH, BB), 256, 0, stream>>>(qkvx, qkvc, qb, kb);
  k_vt<<<dim3((NT + 63) / 64, HH, BB), 256, 0, stream>>>(qkvx, qkvc, vtb);

  // 6) flash attention -> o (written into slot 1)
  k_attn<<<dim3((NT + 63) / 64, HH, BB), 256, 0, stream>>>(qb, kb, vtb, xn, cn);

  // 7) output projections with gated residual -> x2/c2 f32
  k_gemm<2><<<dim3(DD / 128, 32), 256, 0, stream>>>(xn, wt_proj_x, b_proj_x, BB * NX, DD, DD, DD, DD, 0, x2, x, modf, 2 * DD, NX);
  k_gemm<2><<<dim3(DD / 128, 5), 256, 0, stream>>>(cn, wt_proj_c, b_proj_c, BB * NC, DD, DD, DD, DD, 0, c2, c, modf, 5 * DD, NC);

  // 8) plain LN -> bf16
  k_ln<<<dim3(BB * NX), 256, 0, stream>>>(x2, xn, nullptr, 0, 0, NX);
  k_ln<<<dim3(BB * NC), 256, 0, stream>>>(c2, cn, nullptr, 0, 0, NC);

  // 9) MLP (mlp1_x on 256x256 8-wave kernel)
  k_gemm256<1><<<dim3(MHD / 256, (BB * NX) / 256), 512, 0, stream>>>(xn, wt_w1_x, b1_x, MHD, DD, DD, DD, hx);
  k_gemm<1><<<dim3(MHD / 128, 5), 256, 0, stream>>>(cn, wt_w1_c, b1_c, BB * NC, MHD, DD, DD, DD, 0, hc, nullptr, nullptr, 0, 1);

  float* outx = (float*)d_out;
  float* outc = outx + (size_t)BB * NX * DD;
  // mlp2_x: concurrent split-K (z=0: K[0,3072), z=1: K[3072,6144)) -> bf16
  // partials at pb0 / pb0 + PSTRIDE (== pb1, disjoint from live x2/c2) -> reduce
  k_gemm<4><<<dim3(DD / 128, 32, 2), 256, 0, stream>>>(hx, wt_w2_x, b2_x, BB * NX, DD, MHD, MHD, MHD / 2, MHD / 2, pb0, nullptr, nullptr, PSTRIDE, NX);
  k_red<<<dim3(BB * NX), 256, 0, stream>>>(pb0, pb1, x2, b2_x, outx);
  k_gemm<3><<<dim3(DD / 128, 5), 256, 0, stream>>>(hc, wt_w2_c, b2_c, BB * NC, DD, MHD, MHD, MHD, 0, outc, c2, nullptr, 0, NC);
}